// Round 10
// baseline (194.650 us; speedup 1.0000x reference)
//
#include <hip/hip_runtime.h>
#include <stdint.h>

#define Bn 32
#define Nn 256
#define En 512
#define Hn 8
#define Dn 64

typedef __attribute__((ext_vector_type(8))) short bf16x8;   // MFMA A/B frag (4 VGPRs)
typedef __attribute__((ext_vector_type(4))) short bf16x4;
typedef __attribute__((ext_vector_type(4))) float f32x4;    // MFMA C/D frag
typedef __attribute__((ext_vector_type(4))) _Float16 h4f;   // packed fp16 bias frag

__device__ __forceinline__ unsigned short f2bf(float f){
  union{float f; uint32_t i;} v; v.f = f;
  uint32_t i = v.i;
  return (unsigned short)((i + 0x7fffu + ((i>>16)&1u)) >> 16);  // RNE
}

// async global->LDS, 16B per lane. LDS dest = wave-uniform base + lane*16.
__device__ __forceinline__ void stage16(const unsigned short* g,
                                        unsigned short* lds_wave_base,
                                        unsigned short* lds_lane){
#if __has_builtin(__builtin_amdgcn_global_load_lds)
  __builtin_amdgcn_global_load_lds(
      (const __attribute__((address_space(1))) unsigned int*)g,
      (__attribute__((address_space(3))) unsigned int*)lds_wave_base, 16, 0, 0);
  (void)lds_lane;
#else
  *(bf16x8*)lds_lane = *(const bf16x8*)g;
  (void)lds_wave_base;
#endif
}

// ---------------------------------------------------------------------------
// Kernel 0 (fallback path): x fp32 -> bf16.
// ---------------------------------------------------------------------------
__global__ __launch_bounds__(256) void convert_x(
    const float* __restrict__ x, unsigned short* __restrict__ xb){
  size_t i = ((size_t)blockIdx.x * 256 + threadIdx.x) * 8;
  float4 a = *(const float4*)(x + i);
  float4 b = *(const float4*)(x + i + 4);
  bf16x8 p;
  p[0]=(short)f2bf(a.x); p[1]=(short)f2bf(a.y); p[2]=(short)f2bf(a.z); p[3]=(short)f2bf(a.w);
  p[4]=(short)f2bf(b.x); p[5]=(short)f2bf(b.y); p[6]=(short)f2bf(b.z); p[7]=(short)f2bf(b.w);
  *(bf16x8*)(xb + i) = p;
}

// ---------------------------------------------------------------------------
// Kernel P-v2: conversions ONLY (unchanged, verified).
// ---------------------------------------------------------------------------
__global__ __launch_bounds__(256) void convert_all(
    const float* __restrict__ x, unsigned short* __restrict__ xb,
    const float* __restrict__ wq, unsigned short* __restrict__ wqb,
    const float* __restrict__ wo, unsigned short* __restrict__ wob){
  const int bx = blockIdx.x;
  const int tid = threadIdx.x;
  const float* src; unsigned short* dst; size_t i;
  if (bx < 2048)      { src = x;  dst = xb;  i = ((size_t)bx * 256 + tid) * 8; }
  else if (bx < 2432) { src = wq; dst = wqb; i = ((size_t)(bx-2048) * 256 + tid) * 8; }
  else                { src = wo; dst = wob; i = ((size_t)(bx-2432) * 256 + tid) * 8; }
  float4 a = *(const float4*)(src + i);
  float4 b = *(const float4*)(src + i + 4);
  bf16x8 p;
  p[0]=(short)f2bf(a.x); p[1]=(short)f2bf(a.y); p[2]=(short)f2bf(a.z); p[3]=(short)f2bf(a.w);
  p[4]=(short)f2bf(b.x); p[5]=(short)f2bf(b.y); p[6]=(short)f2bf(b.z); p[7]=(short)f2bf(b.w);
  *(bf16x8*)(dst + i) = p;
}

// ---------------------------------------------------------------------------
// Kernel A-v8: round-6/9 body UNCHANGED (BK=64 counted-vmcnt dbuf, 64 KB LDS,
// VGPR~104 — best measured 42.6-44.6 µs), with ONE change: blockIdx->work
// mapping is interleaved, period 11 = {3 qkv + 8 bias} (2816 = 11*256).
// Round-8 proved interleave raises occupancy 17->44%; its regression came
// from the bundled launch_bounds(256,5) (VGPR 40) + tile shrink, both
// reverted here. Single-variable test of dispatch mixing.
// ---------------------------------------------------------------------------
__global__ __launch_bounds__(256) void qkv_bias_gemm(
    const unsigned short* __restrict__ xb, const unsigned short* __restrict__ wqb,
    const float* __restrict__ bq,
    const float* __restrict__ U, const float* __restrict__ w_u,
    const float* __restrict__ b_u,
    unsigned short* __restrict__ q_ws, unsigned short* __restrict__ k_ws,
    unsigned short* __restrict__ v_ws, unsigned short* __restrict__ bias16){
  __shared__ unsigned short smem[32768];   // 64 KB (qkv path); reused by bias path
  const int tid = threadIdx.x;
  const int blk = blockIdx.x;
  const int grp = blk / 11, ph = blk % 11;

  if (ph >= 3) {
    // ---- bias blocks (verified body), interleaved id ----
    float* s_wu = (float*)smem;
    float* s_bu = (float*)(smem + 128);
    if (tid < 64) s_wu[tid] = w_u[tid];
    if (tid < 8)  s_bu[tid] = b_u[tid];
    __syncthreads();
    const int t  = (grp * 8 + (ph - 3)) * 256 + tid;   // 0..524287
    const int m_ = t & 255;
    const int n4 = (t >> 8) & 63;                // n = n4*4 + r
    const int bb = t >> 14;                      // batch
    const float* up = U + ((size_t)(bb*Nn + n4*4)*Nn + m_) * 8;
    float u[4][8];
    #pragma unroll
    for (int r = 0; r < 4; ++r) {
      float4 a = *(const float4*)(up + (size_t)r * (Nn*8));
      float4 c = *(const float4*)(up + (size_t)r * (Nn*8) + 4);
      u[r][0]=a.x; u[r][1]=a.y; u[r][2]=a.z; u[r][3]=a.w;
      u[r][4]=c.x; u[r][5]=c.y; u[r][6]=c.z; u[r][7]=c.w;
    }
    const int    lane_in = ((n4 & 3) * 16 + (m_ & 15)) * 4;
    const size_t tbase   = ((size_t)(n4 >> 2) * 16 + (m_ >> 4)) * 256;
    #pragma unroll
    for (int h = 0; h < 8; ++h) {
      const float bu = s_bu[h];
      float acc[4];
      #pragma unroll
      for (int r = 0; r < 4; ++r) {
        float a = bu;
        #pragma unroll
        for (int id = 0; id < 8; ++id) a += u[r][id] * s_wu[h*8 + id];
        acc[r] = a;
      }
      h4f hv;
      hv[0]=(_Float16)acc[0]; hv[1]=(_Float16)acc[1];
      hv[2]=(_Float16)acc[2]; hv[3]=(_Float16)acc[3];
      *(h4f*)(bias16 + (size_t)(bb*Hn + h) * 65536 + tbase + lane_in) = hv;
    }
    return;
  }

  // ---- qkv blocks (verified qkv_gemm4 body), interleaved id ----
  const int qid = grp * 3 + ph;         // 0..767
  const int bx = qid % 12;              // col tile 0..11
  const int by = qid / 12;              // row tile 0..63
  const int row0 = by * 128, n0 = bx * 128;
  const int lane = tid & 63, wv = tid >> 6;
  const int wr = wv >> 1, wc = wv & 1;
  const int lm = lane & 15, quad = lane >> 4;
  f32x4 acc[4][4] = {};

  auto stage_tile = [&](int buf, int kc){
    const int k0 = kc * 64;
    unsigned short* sa = smem + buf * 8192;
    unsigned short* sb = smem + 16384 + buf * 8192;
    #pragma unroll
    for (int i = 0; i < 4; ++i) {
      const int ci = i*256 + tid;                  // 16B chunk index 0..1023
      const int r = ci >> 3, c = ci & 7;
      const int sc = (c ^ (r & 7)) * 8;            // pre-swizzled source column
      stage16(xb  + (size_t)(row0 + r)*512 + k0 + sc,
              sa + (size_t)(i*256 + wv*64)*8, sa + (size_t)ci*8);
      stage16(wqb + (size_t)(n0  + r)*512 + k0 + sc,
              sb + (size_t)(i*256 + wv*64)*8, sb + (size_t)ci*8);
    }
  };

  stage_tile(0, 0);                      // prologue: 8 loads in flight
  #pragma unroll 1
  for (int kc = 0; kc < 8; ++kc) {
    const int cur = kc & 1;
    if (kc < 7) {
      stage_tile(cur ^ 1, kc + 1);       // 16 in flight
      asm volatile("s_waitcnt vmcnt(8)" ::: "memory");   // wait tile kc only
    } else {
      asm volatile("s_waitcnt vmcnt(0)" ::: "memory");
    }
    __builtin_amdgcn_s_barrier();        // all waves: tile kc resident
    __builtin_amdgcn_sched_barrier(0);
    const unsigned short* sa = smem + cur * 8192;
    const unsigned short* sb = smem + 16384 + cur * 8192;
    #pragma unroll
    for (int ks = 0; ks < 2; ++ks) {
      bf16x8 af[4], bfr[4];
      #pragma unroll
      for (int mt = 0; mt < 4; ++mt) {
        const int r = wr*64 + mt*16 + lm;
        af[mt] = *(const bf16x8*)(sa + (size_t)r*64 + (((ks*4 + quad) ^ (r & 7)) * 8));
      }
      #pragma unroll
      for (int nt = 0; nt < 4; ++nt) {
        const int r = wc*64 + nt*16 + lm;
        bfr[nt] = *(const bf16x8*)(sb + (size_t)r*64 + (((ks*4 + quad) ^ (r & 7)) * 8));
      }
      #pragma unroll
      for (int mt = 0; mt < 4; ++mt)
        #pragma unroll
        for (int nt = 0; nt < 4; ++nt)
          acc[mt][nt] = __builtin_amdgcn_mfma_f32_16x16x32_bf16(af[mt], bfr[nt], acc[mt][nt], 0, 0, 0);
    }
    __builtin_amdgcn_sched_barrier(0);
    __builtin_amdgcn_s_barrier();        // WAR guard (no drain; next loads fly)
  }

  // ---- epilogue: LDS bounce -> coalesced stores. Section uniform per block.
  const int sec = bx >> 2;               // 0=q 1=k 2=v
  float bias[4];
  #pragma unroll
  for (int nt = 0; nt < 4; ++nt) bias[nt] = bq[n0 + wc*64 + nt*16 + lm];
  unsigned short* tile = smem;           // [128][136] (row-major q/k, col-major v)
  if (sec < 2) {
    const float scale = (sec == 0) ? 0.125f : 1.0f;
    #pragma unroll
    for (int nt = 0; nt < 4; ++nt) {
      const int col = wc*64 + nt*16 + lm;
      #pragma unroll
      for (int mt = 0; mt < 4; ++mt)
        #pragma unroll
        for (int r = 0; r < 4; ++r) {
          const int row = wr*64 + mt*16 + quad*4 + r;
          tile[row*136 + col] = f2bf((acc[mt][nt][r] + bias[nt]) * scale);
        }
    }
  } else {
    #pragma unroll
    for (int nt = 0; nt < 4; ++nt) {
      const int col = wc*64 + nt*16 + lm;
      #pragma unroll
      for (int mt = 0; mt < 4; ++mt)
        #pragma unroll
        for (int r = 0; r < 4; ++r) {
          const int row = wr*64 + mt*16 + quad*4 + r;
          tile[col*136 + row] = f2bf(acc[mt][nt][r] + bias[nt]);   // transposed
        }
    }
  }
  __syncthreads();
  if (sec < 2) {
    unsigned short* dst = (sec == 0) ? q_ws : k_ws;
    #pragma unroll
    for (int it = 0; it < 16; ++it) {
      const int rown = it*8 + (tid >> 5);            // 0..127
      const int col  = (tid & 31) * 4;               // 0..124
      bf16x4 vv = *(const bf16x4*)(tile + rown*136 + col);
      const int c = n0 + col, ch = c & 511, h = ch >> 6, d = ch & 63;
      const int grow = row0 + rown, b = grow >> 8, n = grow & 255;
      *(bf16x4*)(dst + (((size_t)b*Hn + h)*Nn + n)*Dn + d) = vv;
    }
  } else {
    const int b = row0 >> 8, nbase = row0 & 255;
    #pragma unroll
    for (int it = 0; it < 16; ++it) {
      const int c  = it*8 + (tid >> 5);              // channel-in-tile 0..127
      const int n4 = (tid & 31) * 4;
      bf16x4 vv = *(const bf16x4*)(tile + c*136 + n4);
      const int ch = (n0 - 1024) + c, h = ch >> 6, d = ch & 63;
      *(bf16x4*)(v_ws + (((size_t)b*Hn + h)*Dn + d)*Nn + nbase + n4) = vv;
    }
  }
}

// ---------------------------------------------------------------------------
// Kernel C-v4: oproj GEMM with counted-vmcnt pipeline (unchanged, verified).
// ---------------------------------------------------------------------------
__global__ __launch_bounds__(256) void oproj_gemm4(
    const unsigned short* __restrict__ o_ws, const unsigned short* __restrict__ wob,
    const float* __restrict__ bo, float* __restrict__ out){
  __shared__ unsigned short smem[24576];   // A dbuf 2x16KB | B dbuf 2x8KB
  const int tid = threadIdx.x;
  const int bx = blockIdx.x;            // col tile 0..7 (64 wide)
  const int by = blockIdx.y;            // row tile 0..63
  const int row0 = by * 128, n0 = bx * 64;
  const int lane = tid & 63, wv = tid >> 6;
  const int wr = wv >> 1, wc = wv & 1;
  const int lm = lane & 15, quad = lane >> 4;
  f32x4 acc[4][2] = {};

  auto stage_tile = [&](int buf, int kc){
    const int k0 = kc * 64;
    unsigned short* sa = smem + buf * 8192;
    unsigned short* sb = smem + 16384 + buf * 4096;
    #pragma unroll
    for (int i = 0; i < 4; ++i) {                  // A: 128x64 = 1024 chunks
      const int ci = i*256 + tid;
      const int r = ci >> 3, c = ci & 7;
      const int sc = (c ^ (r & 7)) * 8;
      stage16(o_ws + (size_t)(row0 + r)*512 + k0 + sc,
              sa + (size_t)(i*256 + wv*64)*8, sa + (size_t)ci*8);
    }
    #pragma unroll
    for (int i = 0; i < 2; ++i) {                  // B: 64x64 = 512 chunks
      const int ci = i*256 + tid;
      const int r = ci >> 3, c = ci & 7;
      const int sc = (c ^ (r & 7)) * 8;
      stage16(wob + (size_t)(n0 + r)*512 + k0 + sc,
              sb + (size_t)(i*256 + wv*64)*8, sb + (size_t)ci*8);
    }
  };

  stage_tile(0, 0);
  #pragma unroll 1
  for (int kc = 0; kc < 8; ++kc) {
    const int cur = kc & 1;
    if (kc < 7) {
      stage_tile(cur ^ 1, kc + 1);
      asm volatile("s_waitcnt vmcnt(6)" ::: "memory");
    } else {
      asm volatile("s_waitcnt vmcnt(0)" ::: "memory");
    }
    __builtin_amdgcn_s_barrier();
    __builtin_amdgcn_sched_barrier(0);
    const unsigned short* sa = smem + cur * 8192;
    const unsigned short* sb = smem + 16384 + cur * 4096;
    #pragma unroll
    for (int ks = 0; ks < 2; ++ks) {
      bf16x8 af[4], bfr[2];
      #pragma unroll
      for (int mt = 0; mt < 4; ++mt) {
        const int r = wr*64 + mt*16 + lm;
        af[mt] = *(const bf16x8*)(sa + (size_t)r*64 + (((ks*4 + quad) ^ (r & 7)) * 8));
      }
      #pragma unroll
      for (int nt = 0; nt < 2; ++nt) {
        const int r = wc*32 + nt*16 + lm;
        bfr[nt] = *(const bf16x8*)(sb + (size_t)r*64 + (((ks*4 + quad) ^ (r & 7)) * 8));
      }
      #pragma unroll
      for (int mt = 0; mt < 4; ++mt)
        #pragma unroll
        for (int nt = 0; nt < 2; ++nt)
          acc[mt][nt] = __builtin_amdgcn_mfma_f32_16x16x32_bf16(af[mt], bfr[nt], acc[mt][nt], 0, 0, 0);
    }
    __builtin_amdgcn_sched_barrier(0);
    __builtin_amdgcn_s_barrier();
  }
  #pragma unroll
  for (int nt = 0; nt < 2; ++nt) {
    int c = n0 + wc*32 + nt*16 + lm;
    float bias = bo[c];
    #pragma unroll
    for (int mt = 0; mt < 4; ++mt)
      #pragma unroll
      for (int r = 0; r < 4; ++r) {
        int grow = row0 + wr*64 + mt*16 + quad*4 + r;
        out[(size_t)grow*512 + c] = acc[mt][nt][r] + bias;
      }
  }
}

// ---------------------------------------------------------------------------
// Kernel B-v4: max-free flash attention with register software pipeline
// (unchanged from round 9 — neutral vs v3, kept).
// ---------------------------------------------------------------------------
__global__ __launch_bounds__(256) void attn_fast(
    const unsigned short* __restrict__ bias16,
    const unsigned short* __restrict__ q_ws, const unsigned short* __restrict__ k_ws,
    const unsigned short* __restrict__ v_ws, unsigned short* __restrict__ o_ws){
  __shared__ unsigned short s_p[4][2][16][40];   // per-wave dual P strip
  const int tid = threadIdx.x;
  const int wv = tid >> 6, lane = tid & 63;
  const int lm = lane & 15, quad = lane >> 4;
  const int bx = blockIdx.x;
  const int g  = (bx & 7) * 8 + ((bx >> 3) >> 4);   // 0..63
  const int qt = (bx >> 3) & 15;
  const int b = g >> 1, hp = g & 1;
  const int h = hp * 4 + wv;
  const size_t hb = (size_t)b * Hn + h;
  const int qt0 = qt * 16;
  const unsigned short* qp = q_ws + (hb*Nn + qt0 + lm) * Dn;   // q pre-scaled 1/8
  const bf16x8 qa0 = *(const bf16x8*)(qp + quad*8);
  const bf16x8 qa1 = *(const bf16x8*)(qp + 32 + quad*8);
  const unsigned short* bt = bias16 + (hb*16 + qt) * 4096 + (size_t)lane*4;
  const unsigned short* kb = k_ws + (hb*Nn + lm) * Dn + quad*8;   // + key*Dn
  const unsigned short* vb = v_ws + (hb*Dn + lm) * Nn + quad*8;   // + d0*16*Nn + ck*32
  f32x4 oa[4] = {};
  float esum[4] = {0.f, 0.f, 0.f, 0.f};
  bf16x8 kf0 = *(const bf16x8*)(kb);
  bf16x8 kf1 = *(const bf16x8*)(kb + 32);
  bf16x8 kf2 = *(const bf16x8*)(kb + 16*Dn);
  bf16x8 kf3 = *(const bf16x8*)(kb + 16*Dn + 32);
  h4f hv0 = *(const h4f*)(bt);
  h4f hv1 = *(const h4f*)(bt + 256);
  #pragma unroll 2
  for (int ck = 0; ck < 8; ++ck) {
    const unsigned short* vp = vb + ck*32;
    const bf16x8 bv0 = *(const bf16x8*)(vp);
    const bf16x8 bv1 = *(const bf16x8*)(vp + 16*Nn);
    const bf16x8 bv2 = *(const bf16x8*)(vp + 32*Nn);
    const bf16x8 bv3 = *(const bf16x8*)(vp + 48*Nn);
    f32x4 la0, la1;
    #pragma unroll
    for (int r = 0; r < 4; ++r) { la0[r] = (float)hv0[r]; la1[r] = (float)hv1[r]; }
    __builtin_amdgcn_s_setprio(1);
    la0 = __builtin_amdgcn_mfma_f32_16x16x32_bf16(qa0, kf0, la0, 0, 0, 0);
    la0 = __builtin_amdgcn_mfma_f32_16x16x32_bf16(qa1, kf1, la0, 0, 0, 0);
    la1 = __builtin_amdgcn_mfma_f32_16x16x32_bf16(qa0, kf2, la1, 0, 0, 0);
    la1 = __builtin_amdgcn_mfma_f32_16x16x32_bf16(qa1, kf3, la1, 0, 0, 0);
    __builtin_amdgcn_s_setprio(0);
    if (ck < 7) {
      const unsigned short* kn = kb + (ck + 1) * 32 * Dn;
      kf0 = *(const bf16x8*)(kn);
      kf1 = *(const bf16x8*)(kn + 32);
      kf2 = *(const bf16x8*)(kn + 16*Dn);
      kf3 = *(const bf16x8*)(kn + 16*Dn + 32);
      hv0 = *(const h4f*)(bt + (ck + 1) * 512);
      hv1 = *(const h4f*)(bt + (ck + 1) * 512 + 256);
    }
    #pragma unroll
    for (int r = 0; r < 4; ++r) {
      la0[r] = __expf(la0[r]);
      la1[r] = __expf(la1[r]);
      esum[r] += la0[r] + la1[r];
    }
    const int ps = ck & 1;
    #pragma unroll
    for (int r = 0; r < 4; ++r) {
      s_p[wv][ps][quad*4+r][lm]      = f2bf(la0[r]);
      s_p[wv][ps][quad*4+r][16 + lm] = f2bf(la1[r]);
    }
    const bf16x8 ap = *(const bf16x8*)&s_p[wv][ps][lm][quad*8];
    __builtin_amdgcn_s_setprio(1);
    oa[0] = __builtin_amdgcn_mfma_f32_16x16x32_bf16(ap, bv0, oa[0], 0, 0, 0);
    oa[1] = __builtin_amdgcn_mfma_f32_16x16x32_bf16(ap, bv1, oa[1], 0, 0, 0);
    oa[2] = __builtin_amdgcn_mfma_f32_16x16x32_bf16(ap, bv2, oa[2], 0, 0, 0);
    oa[3] = __builtin_amdgcn_mfma_f32_16x16x32_bf16(ap, bv3, oa[3], 0, 0, 0);
    __builtin_amdgcn_s_setprio(0);
  }
  #pragma unroll
  for (int r = 0; r < 4; ++r) {
    float s = esum[r];
    #pragma unroll
    for (int msk = 1; msk < 16; msk <<= 1) s += __shfl_xor(s, msk);
    const float inv = 1.0f / s;
    const int n = qt0 + quad*4 + r;
    #pragma unroll
    for (int nt = 0; nt < 4; ++nt)
      o_ws[((size_t)(b*Nn + n))*En + h*64 + nt*16 + lm] = f2bf(oa[nt][r] * inv);
  }
}

// ---------------------------------------------------------------------------
// Fallback kernels (workspace too small). Unchanged, verified.
// ---------------------------------------------------------------------------
__global__ __launch_bounds__(256) void qkv_gemm(
    const unsigned short* __restrict__ xb, const float* __restrict__ wq,
    const float* __restrict__ bq,
    unsigned short* __restrict__ q_ws, unsigned short* __restrict__ k_ws,
    unsigned short* __restrict__ v_ws){
  __shared__ unsigned short s_a[128][40];
  __shared__ unsigned short s_b[128][40];
  const int tid = threadIdx.x;
  const int bx = blockIdx.x;
  const int by = blockIdx.y;
  const int row0 = by * 128, n0 = bx * 128;
  const int lane = tid & 63, wv = tid >> 6;
  const int wr = wv >> 1, wc = wv & 1;
  const int lm = lane & 15, quad = lane >> 4;
  const int sr = tid >> 3, sc4 = (tid & 7) * 4;
  f32x4 acc[4][4] = {};
  for (int kc = 0; kc < 16; ++kc) {
    const int k0 = kc * 32;
    __syncthreads();
    #pragma unroll
    for (int i = 0; i < 2; ++i) {
      int g = tid * 2 + i;
      int r = g >> 2, c8 = (g & 3) * 8;
      *(bf16x8*)&s_a[r][c8] = *(const bf16x8*)(xb + (size_t)(row0 + r)*512 + k0 + c8);
    }
    #pragma unroll
    for (int i = 0; i < 4; ++i) {
      int r = sr + i * 32;
      float4 vb = *(const float4*)(wq + (size_t)(n0 + r) * 512 + k0 + sc4);
      bf16x4 pb;
      pb[0]=(short)f2bf(vb.x); pb[1]=(short)f2bf(vb.y); pb[2]=(short)f2bf(vb.z); pb[3]=(short)f2bf(vb.w);
      *(bf16x4*)&s_b[r][sc4] = pb;
    }
    __syncthreads();
    bf16x8 af[4], bfr[4];
    #pragma unroll
    for (int mt = 0; mt < 4; ++mt) af[mt]  = *(const bf16x8*)&s_a[wr*64 + mt*16 + lm][quad*8];
    #pragma unroll
    for (int nt = 0; nt < 4; ++nt) bfr[nt] = *(const bf16x8*)&s_b[wc*64 + nt*16 + lm][quad*8];
    #pragma unroll
    for (int mt = 0; mt < 4; ++mt)
      #pragma unroll
      for (int nt = 0; nt < 4; ++nt)
        acc[mt][nt] = __builtin_amdgcn_mfma_f32_16x16x32_bf16(af[mt], bfr[nt], acc[mt][nt], 0, 0, 0);
  }
  #pragma unroll
  for (int nt = 0; nt < 4; ++nt) {
    int c = n0 + wc*64 + nt*16 + lm;
    float bias = bq[c];
    int sec = c >> 9, ch = c & 511, h = ch >> 6, d = ch & 63;
    #pragma unroll
    for (int mt = 0; mt < 4; ++mt) {
      #pragma unroll
      for (int r = 0; r < 4; ++r) {
        int grow = row0 + wr*64 + mt*16 + quad*4 + r;
        int b = grow >> 8, n = grow & 255;
        float val = acc[mt][nt][r] + bias;
        if (sec == 0)      q_ws[(((size_t)b*Hn + h)*Nn + n)*Dn + d] = f2bf(val * 0.125f);
        else if (sec == 1) k_ws[(((size_t)b*Hn + h)*Nn + n)*Dn + d] = f2bf(val);
        else               v_ws[(((size_t)b*Hn + h)*Dn + d)*Nn + n] = f2bf(val);
      }
    }
  }
}

__global__ __launch_bounds__(256) void attn_kernel(
    const float* __restrict__ U, const float* __restrict__ w_u, const float* __restrict__ b_u,
    const unsigned short* __restrict__ q_ws, const unsigned short* __restrict__ k_ws,
    const unsigned short* __restrict__ v_ws, unsigned short* __restrict__ o_ws){
  __shared__ unsigned short s_p[4][2][16][40];
  __shared__ float s_wu[64];
  __shared__ float s_bu[8];
  const int tid = threadIdx.x;
  const int wv = tid >> 6, lane = tid & 63;
  const int lm = lane & 15, quad = lane >> 4;
  const int blk = blockIdx.x;
  const int b = blk >> 4, qt0 = (blk & 15) * 16;
  if (tid < 64) s_wu[tid] = w_u[tid];
  if (tid < 8)  s_bu[tid] = b_u[tid];
  __syncthreads();
  const int h0 = wv * 2, h1 = h0 + 1;
  const size_t hb0 = (size_t)b * Hn + h0, hb1 = hb0 + 1;
  float wu0[8], wu1[8];
  #pragma unroll
  for (int i = 0; i < 8; ++i) { wu0[i] = s_wu[h0*8 + i]; wu1[i] = s_wu[h1*8 + i]; }
  const float bu0 = s_bu[h0], bu1 = s_bu[h1];
  const unsigned short* q0p = q_ws + (hb0*Nn + qt0 + lm)*Dn;
  const unsigned short* q1p = q_ws + (hb1*Nn + qt0 + lm)*Dn;
  const bf16x8 qa0 = *(const bf16x8*)(q0p + quad*8);
  const bf16x8 qa1 = *(const bf16x8*)(q0p + 32 + quad*8);
  const bf16x8 qb0 = *(const bf16x8*)(q1p + quad*8);
  const bf16x8 qb1 = *(const bf16x8*)(q1p + 32 + quad*8);
  f32x4 oa[4] = {}, ob[4] = {};
  float m0[4], m1[4], l0[4], l1[4];
  #pragma unroll
  for (int r = 0; r < 4; ++r) { m0[r] = m1[r] = -3.0e38f; l0[r] = l1[r] = 0.f; }
  const float* Ub = U + ((size_t)(b*Nn + qt0)) * Nn * 8;
  #pragma unroll 1
  for (int ck = 0; ck < 8; ++ck) {
    f32x4 la0, la1, lb0, lb1;
    #pragma unroll
    for (int t = 0; t < 2; ++t) {
      const int key0 = ck*32 + t*16;
      f32x4 c0, c1;
      #pragma unroll
      for (int r = 0; r < 4; ++r) {
        const float4* up = (const float4*)(Ub + ((size_t)(quad*4+r)*Nn + key0 + lm)*8);
        float4 ua = up[0], uc = up[1];
        c0[r] = bu0 + ua.x*wu0[0] + ua.y*wu0[1] + ua.z*wu0[2] + ua.w*wu0[3]
                    + uc.x*wu0[4] + uc.y*wu0[5] + uc.z*wu0[6] + uc.w*wu0[7];
        c1[r] = bu1 + ua.x*wu1[0] + ua.y*wu1[1] + ua.z*wu1[2] + ua.w*wu1[3]
                    + uc.x*wu1[4] + uc.y*wu1[5] + uc.z*wu1[6] + uc.w*wu1[7];
      }
      const unsigned short* k0p = k_ws + (hb0*Nn + key0 + lm)*Dn;
      const unsigned short* k1p = k_ws + (hb1*Nn + key0 + lm)*Dn;
      bf16x8 kf;
      kf = *(const bf16x8*)(k0p + quad*8);
      c0 = __builtin_amdgcn_mfma_f32_16x16x32_bf16(qa0, kf, c0, 0, 0, 0);
      kf = *(const bf16x8*)(k0p + 32 + quad*8);
      c0 = __builtin_amdgcn_mfma_f32_16x16x32_bf16(qa1, kf, c0, 0, 0, 0);
      kf = *(const bf16x8*)(k1p + quad*8);
      c1 = __builtin_amdgcn_mfma_f32_16x16x32_bf16(qb0, kf, c1, 0, 0, 0);
      kf = *(const bf16x8*)(k1p + 32 + quad*8);
      c1 = __builtin_amdgcn_mfma_f32_16x16x32_bf16(qb1, kf, c1, 0, 0, 0);
      if (t == 0) { la0 = c0; lb0 = c1; } else { la1 = c0; lb1 = c1; }
    }
    #pragma unroll
    for (int r = 0; r < 4; ++r) {
      {
        float tm = fmaxf(la0[r], la1[r]);
        #pragma unroll
        for (int msk = 1; msk < 16; msk <<= 1) tm = fmaxf(tm, __shfl_xor(tm, msk));
        float mn = fmaxf(m0[r], tm);
        float al = __expf(m0[r] - mn);
        m0[r] = mn;
        float e0 = __expf(la0[r] - mn), e1 = __expf(la1[r] - mn);
        la0[r] = e0; la1[r] = e1;
        float s = e0 + e1;
        #pragma unroll
        for (int msk = 1; msk < 16; msk <<= 1) s += __shfl_xor(s, msk);
        l0[r] = l0[r] * al + s;
        #pragma unroll
        for (int nt = 0; nt < 4; ++nt) oa[nt][r] *= al;
      }
      {
        float tm = fmaxf(lb0[r], lb1[r]);
        #pragma unroll
        for (int msk = 1; msk < 16; msk <<= 1) tm = fmaxf(tm, __shfl_xor(tm, msk));
        float mn = fmaxf(m1[r], tm);
        float al = __expf(m1[r] - mn);
        m1[r] = mn;
        float e0 = __expf(lb0[r] - mn), e1 = __expf(lb1[r] - mn);
        lb0[r] = e0; lb1[r] = e1;
        float s = e0 + e1;
        #pragma unroll
        for (int msk = 1; msk < 16; msk <<= 1) s += __shfl_xor(s, msk);
        l1[r] = l1[r] * al + s;
        #pragma unroll
        for (int nt = 0; nt < 4; ++nt) ob[nt][r] *= al;
      }
    }
    #pragma unroll
    for (int r = 0; r < 4; ++r) {
      s_p[wv][0][quad*4+r][lm]      = f2bf(la0[r]);
      s_p[wv][0][quad*4+r][16 + lm] = f2bf(la1[r]);
      s_p[wv][1][quad*4+r][lm]      = f2bf(lb0[r]);
      s_p[wv][1][quad*4+r][16 + lm] = f2bf(lb1[r]);
    }
    const bf16x8 ap0 = *(const bf16x8*)&s_p[wv][0][lm][quad*8];
    const bf16x8 ap1 = *(const bf16x8*)&s_p[wv][1][lm][quad*8];
    #pragma unroll
    for (int nt = 0; nt < 4; ++nt) {
      bf16x8 bv = *(const bf16x8*)(v_ws + (hb0*Dn + nt*16 + lm)*Nn + ck*32 + quad*8);
      oa[nt] = __builtin_amdgcn_mfma_f32_16x16x32_bf16(ap0, bv, oa[nt], 0, 0, 0);
      bv = *(const bf16x8*)(v_ws + (hb1*Dn + nt*16 + lm)*Nn + ck*32 + quad*8);
      ob[nt] = __builtin_amdgcn_mfma_f32_16x16x32_bf16(ap1, bv, ob[nt], 0, 0, 0);
    }
  }
  #pragma unroll
  for (int r = 0; r < 4; ++r) {
    const float i0 = 1.0f / l0[r], i1 = 1.0f / l1[r];
    const int n = qt0 + quad*4 + r;
    #pragma unroll
    for (int nt = 0; nt < 4; ++nt) {
      o_ws[((size_t)(b*Nn + n))*En + h0*64 + nt*16 + lm] = f2bf(oa[nt][r] * i0);
      o_ws[((size_t)(b*Nn + n))*En + h1*64 + nt*16 + lm] = f2bf(ob[nt][r] * i1);
    }
  }
}

__global__ __launch_bounds__(256) void oproj_gemm(
    const unsigned short* __restrict__ o_ws, const float* __restrict__ wo,
    const float* __restrict__ bo, float* __restrict__ out){
  __shared__ unsigned short s_a[128][40];
  __shared__ unsigned short s_b[128][40];
  const int tid = threadIdx.x;
  const int bx = blockIdx.x;
  const int by = blockIdx.y;
  const int row0 = by * 128, n0 = bx * 128;
  const int lane = tid & 63, wv = tid >> 6;
  const int wr = wv >> 1, wc = wv & 1;
  const int lm = lane & 15, quad = lane >> 4;
  const int sr = tid >> 3, sc4 = (tid & 7) * 4;
  f32x4 acc[4][4] = {};
  for (int kc = 0; kc < 16; ++kc) {
    const int k0 = kc * 32;
    __syncthreads();
    #pragma unroll
    for (int i = 0; i < 2; ++i) {
      int g = tid * 2 + i;
      int r = g >> 2, c8 = (g & 3) * 8;
      *(bf16x8*)&s_a[r][c8] = *(const bf16x8*)(o_ws + (size_t)(row0 + r)*512 + k0 + c8);
    }
    #pragma unroll
    for (int i = 0; i < 4; ++i) {
      int r = sr + i * 32;
      float4 vb = *(const float4*)(wo + (size_t)(n0 + r) * 512 + k0 + sc4);
      bf16x4 pb;
      pb[0]=(short)f2bf(vb.x); pb[1]=(short)f2bf(vb.y); pb[2]=(short)f2bf(vb.z); pb[3]=(short)f2bf(vb.w);
      *(bf16x4*)&s_b[r][sc4] = pb;
    }
    __syncthreads();
    bf16x8 af[4], bfr[4];
    #pragma unroll
    for (int mt = 0; mt < 4; ++mt) af[mt]  = *(const bf16x8*)&s_a[wr*64 + mt*16 + lm][quad*8];
    #pragma unroll
    for (int nt = 0; nt < 4; ++nt) bfr[nt] = *(const bf16x8*)&s_b[wc*64 + nt*16 + lm][quad*8];
    #pragma unroll
    for (int mt = 0; mt < 4; ++mt)
      #pragma unroll
      for (int nt = 0; nt < 4; ++nt)
        acc[mt][nt] = __builtin_amdgcn_mfma_f32_16x16x32_bf16(af[mt], bfr[nt], acc[mt][nt], 0, 0, 0);
  }
  #pragma unroll
  for (int nt = 0; nt < 4; ++nt) {
    int c = n0 + wc*64 + nt*16 + lm;
    float bias = bo[c];
    #pragma unroll
    for (int mt = 0; mt < 4; ++mt)
      #pragma unroll
      for (int r = 0; r < 4; ++r) {
        int grow = row0 + wr*64 + mt*16 + quad*4 + r;
        out[(size_t)grow*512 + c] = acc[mt][nt][r] + bias;
      }
  }
}

extern "C" void kernel_launch(void* const* d_in, const int* in_sizes, int n_in,
                              void* d_out, int out_size, void* d_ws, size_t ws_size,
                              hipStream_t stream) {
  const float* x     = (const float*)d_in[0];
  const float* U     = (const float*)d_in[1];
  const float* w_qkv = (const float*)d_in[2];
  const float* b_qkv = (const float*)d_in[3];
  const float* w_out = (const float*)d_in[4];
  const float* b_out = (const float*)d_in[5];
  const float* w_u   = (const float*)d_in[6];
  const float* b_u   = (const float*)d_in[7];
  float* out = (float*)d_out;

  const size_t per = (size_t)Bn * Hn * Nn * Dn;       // 4,194,304 elements
  unsigned short* q_ws = (unsigned short*)d_ws;
  unsigned short* k_ws = q_ws + per;
  unsigned short* v_ws = k_ws + per;                  // transposed [B,H,D,N]
  unsigned short* o_ws = v_ws + per;                  // [B,N,E]; doubles as x_bf16 before attn
  unsigned short* bias16 = o_ws + per;                // fp16 frag-packed bias, 32 MiB
  unsigned short* wqb = bias16 + (size_t)Bn*Hn*Nn*Nn; // bf16 w_qkv, 1.5 MiB
  unsigned short* wob = wqb + (size_t)3*En*En;        // bf16 w_out, 0.5 MiB

  const size_t need = (per*4 + (size_t)Bn*Hn*Nn*Nn + (size_t)3*En*En + (size_t)En*En) * 2;

  if (ws_size >= need) {
    convert_all<<<dim3(2560),  dim3(256), 0, stream>>>(x, o_ws, w_qkv, wqb, w_out, wob);
    qkv_bias_gemm<<<dim3(2816), dim3(256), 0, stream>>>(o_ws, wqb, b_qkv, U, w_u, b_u,
                                                        q_ws, k_ws, v_ws, bias16);
    attn_fast <<<dim3(1024),   dim3(256), 0, stream>>>(bias16, q_ws, k_ws, v_ws, o_ws);
    oproj_gemm4<<<dim3(8, 64), dim3(256), 0, stream>>>(o_ws, wob, b_out, out);
  } else {
    convert_x <<<dim3(2048),  dim3(256), 0, stream>>>(x, o_ws);
    qkv_gemm  <<<dim3(12, 64), dim3(256), 0, stream>>>(o_ws, w_qkv, b_qkv, q_ws, k_ws, v_ws);
    attn_kernel<<<dim3(Bn * 16), dim3(256), 0, stream>>>(U, w_u, b_u, q_ws, k_ws, v_ws, o_ws);
    oproj_gemm<<<dim3(4, 64), dim3(256), 0, stream>>>(o_ws, w_out, b_out, out);
  }
}

// Round 12
// 180.546 us; speedup vs baseline: 1.0781x; 1.0781x over previous
//
#include <hip/hip_runtime.h>
#include <stdint.h>

#define Bn 32
#define Nn 256
#define En 512
#define Hn 8
#define Dn 64

typedef __attribute__((ext_vector_type(8))) short bf16x8;   // MFMA A/B frag (4 VGPRs)
typedef __attribute__((ext_vector_type(4))) short bf16x4;
typedef __attribute__((ext_vector_type(4))) float f32x4;    // MFMA C/D frag
typedef __attribute__((ext_vector_type(4))) _Float16 h4f;   // packed fp16 bias frag

__device__ __forceinline__ unsigned short f2bf(float f){
  union{float f; uint32_t i;} v; v.f = f;
  uint32_t i = v.i;
  return (unsigned short)((i + 0x7fffu + ((i>>16)&1u)) >> 16);  // RNE
}

// async global->LDS, 16B per lane. LDS dest = wave-uniform base + lane*16.
__device__ __forceinline__ void stage16(const unsigned short* g,
                                        unsigned short* lds_wave_base,
                                        unsigned short* lds_lane){
#if __has_builtin(__builtin_amdgcn_global_load_lds)
  __builtin_amdgcn_global_load_lds(
      (const __attribute__((address_space(1))) unsigned int*)g,
      (__attribute__((address_space(3))) unsigned int*)lds_wave_base, 16, 0, 0);
  (void)lds_lane;
#else
  *(bf16x8*)lds_lane = *(const bf16x8*)g;
  (void)lds_wave_base;
#endif
}

// ---------------------------------------------------------------------------
// Kernel 0 (fallback path): x fp32 -> bf16.
// ---------------------------------------------------------------------------
__global__ __launch_bounds__(256) void convert_x(
    const float* __restrict__ x, unsigned short* __restrict__ xb){
  size_t i = ((size_t)blockIdx.x * 256 + threadIdx.x) * 8;
  float4 a = *(const float4*)(x + i);
  float4 b = *(const float4*)(x + i + 4);
  bf16x8 p;
  p[0]=(short)f2bf(a.x); p[1]=(short)f2bf(a.y); p[2]=(short)f2bf(a.z); p[3]=(short)f2bf(a.w);
  p[4]=(short)f2bf(b.x); p[5]=(short)f2bf(b.y); p[6]=(short)f2bf(b.z); p[7]=(short)f2bf(b.w);
  *(bf16x8*)(xb + i) = p;
}

// ---------------------------------------------------------------------------
// Kernel P-v2: conversions ONLY (unchanged, verified).
// ---------------------------------------------------------------------------
__global__ __launch_bounds__(256) void convert_all(
    const float* __restrict__ x, unsigned short* __restrict__ xb,
    const float* __restrict__ wq, unsigned short* __restrict__ wqb,
    const float* __restrict__ wo, unsigned short* __restrict__ wob){
  const int bx = blockIdx.x;
  const int tid = threadIdx.x;
  const float* src; unsigned short* dst; size_t i;
  if (bx < 2048)      { src = x;  dst = xb;  i = ((size_t)bx * 256 + tid) * 8; }
  else if (bx < 2432) { src = wq; dst = wqb; i = ((size_t)(bx-2048) * 256 + tid) * 8; }
  else                { src = wo; dst = wob; i = ((size_t)(bx-2432) * 256 + tid) * 8; }
  float4 a = *(const float4*)(src + i);
  float4 b = *(const float4*)(src + i + 4);
  bf16x8 p;
  p[0]=(short)f2bf(a.x); p[1]=(short)f2bf(a.y); p[2]=(short)f2bf(a.z); p[3]=(short)f2bf(a.w);
  p[4]=(short)f2bf(b.x); p[5]=(short)f2bf(b.y); p[6]=(short)f2bf(b.z); p[7]=(short)f2bf(b.w);
  *(bf16x8*)(dst + i) = p;
}

// ---------------------------------------------------------------------------
// Kernel A-v9: round-9 body (sequential qkv/bias mapping — best measured),
// with NEW packed K/V output layouts for coalesced attn reads:
//   K'[b,h,dg,key,8]  (dg = d>>3)  elem ((hb*8+dg)*256+key)*8 + (d&7)
//   V'[b,h,kg,d,8]    (kg = key>>3) elem ((hb*32+kg)*64+d)*8 + (key&7)
// Epilogue stores become lane-contiguous 16B runs (1KB/instruction).
// ---------------------------------------------------------------------------
__global__ __launch_bounds__(256) void qkv_bias_gemm(
    const unsigned short* __restrict__ xb, const unsigned short* __restrict__ wqb,
    const float* __restrict__ bq,
    const float* __restrict__ U, const float* __restrict__ w_u,
    const float* __restrict__ b_u,
    unsigned short* __restrict__ q_ws, unsigned short* __restrict__ k_ws,
    unsigned short* __restrict__ v_ws, unsigned short* __restrict__ bias16){
  __shared__ unsigned short smem[32768];   // 64 KB (qkv path); reused by bias path
  const int tid = threadIdx.x;
  const int blk = blockIdx.x;

  if (blk >= 768) {
    // ---- bias blocks (verified body) ----
    float* s_wu = (float*)smem;
    float* s_bu = (float*)(smem + 128);
    if (tid < 64) s_wu[tid] = w_u[tid];
    if (tid < 8)  s_bu[tid] = b_u[tid];
    __syncthreads();
    const int t  = (blk - 768) * 256 + tid;      // 0..524287
    const int m_ = t & 255;
    const int n4 = (t >> 8) & 63;                // n = n4*4 + r
    const int bb = t >> 14;                      // batch
    const float* up = U + ((size_t)(bb*Nn + n4*4)*Nn + m_) * 8;
    float u[4][8];
    #pragma unroll
    for (int r = 0; r < 4; ++r) {
      float4 a = *(const float4*)(up + (size_t)r * (Nn*8));
      float4 c = *(const float4*)(up + (size_t)r * (Nn*8) + 4);
      u[r][0]=a.x; u[r][1]=a.y; u[r][2]=a.z; u[r][3]=a.w;
      u[r][4]=c.x; u[r][5]=c.y; u[r][6]=c.z; u[r][7]=c.w;
    }
    const int    lane_in = ((n4 & 3) * 16 + (m_ & 15)) * 4;
    const size_t tbase   = ((size_t)(n4 >> 2) * 16 + (m_ >> 4)) * 256;
    #pragma unroll
    for (int h = 0; h < 8; ++h) {
      const float bu = s_bu[h];
      float acc[4];
      #pragma unroll
      for (int r = 0; r < 4; ++r) {
        float a = bu;
        #pragma unroll
        for (int id = 0; id < 8; ++id) a += u[r][id] * s_wu[h*8 + id];
        acc[r] = a;
      }
      h4f hv;
      hv[0]=(_Float16)acc[0]; hv[1]=(_Float16)acc[1];
      hv[2]=(_Float16)acc[2]; hv[3]=(_Float16)acc[3];
      *(h4f*)(bias16 + (size_t)(bb*Hn + h) * 65536 + tbase + lane_in) = hv;
    }
    return;
  }

  // ---- qkv blocks (verified pipeline body) ----
  const int bx = blk % 12;              // col tile 0..11
  const int by = blk / 12;              // row tile 0..63
  const int row0 = by * 128, n0 = bx * 128;
  const int lane = tid & 63, wv = tid >> 6;
  const int wr = wv >> 1, wc = wv & 1;
  const int lm = lane & 15, quad = lane >> 4;
  f32x4 acc[4][4] = {};

  auto stage_tile = [&](int buf, int kc){
    const int k0 = kc * 64;
    unsigned short* sa = smem + buf * 8192;
    unsigned short* sb = smem + 16384 + buf * 8192;
    #pragma unroll
    for (int i = 0; i < 4; ++i) {
      const int ci = i*256 + tid;                  // 16B chunk index 0..1023
      const int r = ci >> 3, c = ci & 7;
      const int sc = (c ^ (r & 7)) * 8;            // pre-swizzled source column
      stage16(xb  + (size_t)(row0 + r)*512 + k0 + sc,
              sa + (size_t)(i*256 + wv*64)*8, sa + (size_t)ci*8);
      stage16(wqb + (size_t)(n0  + r)*512 + k0 + sc,
              sb + (size_t)(i*256 + wv*64)*8, sb + (size_t)ci*8);
    }
  };

  stage_tile(0, 0);                      // prologue: 8 loads in flight
  #pragma unroll 1
  for (int kc = 0; kc < 8; ++kc) {
    const int cur = kc & 1;
    if (kc < 7) {
      stage_tile(cur ^ 1, kc + 1);       // 16 in flight
      asm volatile("s_waitcnt vmcnt(8)" ::: "memory");   // wait tile kc only
    } else {
      asm volatile("s_waitcnt vmcnt(0)" ::: "memory");
    }
    __builtin_amdgcn_s_barrier();        // all waves: tile kc resident
    __builtin_amdgcn_sched_barrier(0);
    const unsigned short* sa = smem + cur * 8192;
    const unsigned short* sb = smem + 16384 + cur * 8192;
    #pragma unroll
    for (int ks = 0; ks < 2; ++ks) {
      bf16x8 af[4], bfr[4];
      #pragma unroll
      for (int mt = 0; mt < 4; ++mt) {
        const int r = wr*64 + mt*16 + lm;
        af[mt] = *(const bf16x8*)(sa + (size_t)r*64 + (((ks*4 + quad) ^ (r & 7)) * 8));
      }
      #pragma unroll
      for (int nt = 0; nt < 4; ++nt) {
        const int r = wc*64 + nt*16 + lm;
        bfr[nt] = *(const bf16x8*)(sb + (size_t)r*64 + (((ks*4 + quad) ^ (r & 7)) * 8));
      }
      #pragma unroll
      for (int mt = 0; mt < 4; ++mt)
        #pragma unroll
        for (int nt = 0; nt < 4; ++nt)
          acc[mt][nt] = __builtin_amdgcn_mfma_f32_16x16x32_bf16(af[mt], bfr[nt], acc[mt][nt], 0, 0, 0);
    }
    __builtin_amdgcn_sched_barrier(0);
    __builtin_amdgcn_s_barrier();        // WAR guard (no drain; next loads fly)
  }

  // ---- epilogue: LDS bounce -> coalesced stores. Section uniform per block.
  const int sec = bx >> 2;               // 0=q 1=k 2=v
  float bias[4];
  #pragma unroll
  for (int nt = 0; nt < 4; ++nt) bias[nt] = bq[n0 + wc*64 + nt*16 + lm];
  unsigned short* tile = smem;           // q/k: [row=n][col=ch] *136; v: [col=ch][row=n] *136
  if (sec < 2) {
    const float scale = (sec == 0) ? 0.125f : 1.0f;
    #pragma unroll
    for (int nt = 0; nt < 4; ++nt) {
      const int col = wc*64 + nt*16 + lm;
      #pragma unroll
      for (int mt = 0; mt < 4; ++mt)
        #pragma unroll
        for (int r = 0; r < 4; ++r) {
          const int row = wr*64 + mt*16 + quad*4 + r;
          tile[row*136 + col] = f2bf((acc[mt][nt][r] + bias[nt]) * scale);
        }
    }
  } else {
    #pragma unroll
    for (int nt = 0; nt < 4; ++nt) {
      const int col = wc*64 + nt*16 + lm;
      #pragma unroll
      for (int mt = 0; mt < 4; ++mt)
        #pragma unroll
        for (int r = 0; r < 4; ++r) {
          const int row = wr*64 + mt*16 + quad*4 + r;
          tile[col*136 + row] = f2bf(acc[mt][nt][r] + bias[nt]);   // transposed
        }
    }
  }
  __syncthreads();
  const int b = row0 >> 8, nbase = row0 & 255;
  if (sec == 0) {
    // q: old row-major [b,h,n,d] layout (read once per attn block; keep)
    #pragma unroll
    for (int it = 0; it < 16; ++it) {
      const int rown = it*8 + (tid >> 5);            // 0..127
      const int col  = (tid & 31) * 4;               // 0..124
      bf16x4 vv = *(const bf16x4*)(tile + rown*136 + col);
      const int ch = (n0 + col) & 511, h = ch >> 6, d = ch & 63;
      const int n = nbase + rown;
      *(bf16x4*)(q_ws + (((size_t)b*Hn + h)*Nn + n)*Dn + d) = vv;
    }
  } else if (sec == 1) {
    // k: packed K'[b,h,dg,key,8]; 16B/lane, lane-contiguous over key
    const int h0k = (n0 - 512) >> 6;                 // two heads h0k, h0k+1
    const size_t hbk = (size_t)b*Hn + h0k;
    #pragma unroll
    for (int it = 0; it < 8; ++it) {
      const int idx = it*256 + tid;
      const int n = idx & 127;                       // key within tile
      const int combo = idx >> 7;                    // 0..15
      const int hh = combo >> 3, dg = combo & 7;
      bf16x8 vv = *(const bf16x8*)(tile + n*136 + hh*64 + dg*8);
      *(bf16x8*)(k_ws + (((hbk + hh)*8 + dg)*256 + nbase + n)*8) = vv;
    }
  } else {
    // v: packed V'[b,h,kg,d,8]; 16B/lane, lane-contiguous over d
    const int h0v = (n0 - 1024) >> 6;
    const size_t hbv = (size_t)b*Hn + h0v;
    #pragma unroll
    for (int it = 0; it < 8; ++it) {
      const int idx = it*256 + tid;
      const int d = idx & 63;
      const int kgl = (idx >> 6) & 15;               // local key-group (128 keys)
      const int hh = idx >> 10;
      bf16x8 vv = *(const bf16x8*)(tile + (hh*64 + d)*136 + kgl*8);
      *(bf16x8*)(v_ws + (((hbv + hh)*32 + (nbase >> 3) + kgl)*64 + d)*8) = vv;
    }
  }
}

// ---------------------------------------------------------------------------
// Kernel C-v4: oproj GEMM with counted-vmcnt pipeline (unchanged, verified).
// ---------------------------------------------------------------------------
__global__ __launch_bounds__(256) void oproj_gemm4(
    const unsigned short* __restrict__ o_ws, const unsigned short* __restrict__ wob,
    const float* __restrict__ bo, float* __restrict__ out){
  __shared__ unsigned short smem[24576];   // A dbuf 2x16KB | B dbuf 2x8KB
  const int tid = threadIdx.x;
  const int bx = blockIdx.x;            // col tile 0..7 (64 wide)
  const int by = blockIdx.y;            // row tile 0..63
  const int row0 = by * 128, n0 = bx * 64;
  const int lane = tid & 63, wv = tid >> 6;
  const int wr = wv >> 1, wc = wv & 1;
  const int lm = lane & 15, quad = lane >> 4;
  f32x4 acc[4][2] = {};

  auto stage_tile = [&](int buf, int kc){
    const int k0 = kc * 64;
    unsigned short* sa = smem + buf * 8192;
    unsigned short* sb = smem + 16384 + buf * 4096;
    #pragma unroll
    for (int i = 0; i < 4; ++i) {                  // A: 128x64 = 1024 chunks
      const int ci = i*256 + tid;
      const int r = ci >> 3, c = ci & 7;
      const int sc = (c ^ (r & 7)) * 8;
      stage16(o_ws + (size_t)(row0 + r)*512 + k0 + sc,
              sa + (size_t)(i*256 + wv*64)*8, sa + (size_t)ci*8);
    }
    #pragma unroll
    for (int i = 0; i < 2; ++i) {                  // B: 64x64 = 512 chunks
      const int ci = i*256 + tid;
      const int r = ci >> 3, c = ci & 7;
      const int sc = (c ^ (r & 7)) * 8;
      stage16(wob + (size_t)(n0 + r)*512 + k0 + sc,
              sb + (size_t)(i*256 + wv*64)*8, sb + (size_t)ci*8);
    }
  };

  stage_tile(0, 0);
  #pragma unroll 1
  for (int kc = 0; kc < 8; ++kc) {
    const int cur = kc & 1;
    if (kc < 7) {
      stage_tile(cur ^ 1, kc + 1);
      asm volatile("s_waitcnt vmcnt(6)" ::: "memory");
    } else {
      asm volatile("s_waitcnt vmcnt(0)" ::: "memory");
    }
    __builtin_amdgcn_s_barrier();
    __builtin_amdgcn_sched_barrier(0);
    const unsigned short* sa = smem + cur * 8192;
    const unsigned short* sb = smem + 16384 + cur * 4096;
    #pragma unroll
    for (int ks = 0; ks < 2; ++ks) {
      bf16x8 af[4], bfr[2];
      #pragma unroll
      for (int mt = 0; mt < 4; ++mt) {
        const int r = wr*64 + mt*16 + lm;
        af[mt] = *(const bf16x8*)(sa + (size_t)r*64 + (((ks*4 + quad) ^ (r & 7)) * 8));
      }
      #pragma unroll
      for (int nt = 0; nt < 2; ++nt) {
        const int r = wc*32 + nt*16 + lm;
        bfr[nt] = *(const bf16x8*)(sb + (size_t)r*64 + (((ks*4 + quad) ^ (r & 7)) * 8));
      }
      #pragma unroll
      for (int mt = 0; mt < 4; ++mt)
        #pragma unroll
        for (int nt = 0; nt < 2; ++nt)
          acc[mt][nt] = __builtin_amdgcn_mfma_f32_16x16x32_bf16(af[mt], bfr[nt], acc[mt][nt], 0, 0, 0);
    }
    __builtin_amdgcn_sched_barrier(0);
    __builtin_amdgcn_s_barrier();
  }
  #pragma unroll
  for (int nt = 0; nt < 2; ++nt) {
    int c = n0 + wc*32 + nt*16 + lm;
    float bias = bo[c];
    #pragma unroll
    for (int mt = 0; mt < 4; ++mt)
      #pragma unroll
      for (int r = 0; r < 4; ++r) {
        int grow = row0 + wr*64 + mt*16 + quad*4 + r;
        out[(size_t)grow*512 + c] = acc[mt][nt][r] + bias;
      }
  }
}

// ---------------------------------------------------------------------------
// Kernel B-v5: max-free pipelined flash attention reading PACKED K'/V'.
// K frag: dg=quad, key=lm -> 256B-contiguous per quad group (4 transactions
// per load vs 16 with the old row-major layout). V frag likewise.
// ---------------------------------------------------------------------------
__global__ __launch_bounds__(256) void attn_fast(
    const unsigned short* __restrict__ bias16,
    const unsigned short* __restrict__ q_ws, const unsigned short* __restrict__ k_ws,
    const unsigned short* __restrict__ v_ws, unsigned short* __restrict__ o_ws){
  __shared__ unsigned short s_p[4][2][16][40];   // per-wave dual P strip
  const int tid = threadIdx.x;
  const int wv = tid >> 6, lane = tid & 63;
  const int lm = lane & 15, quad = lane >> 4;
  const int bx = blockIdx.x;
  const int g  = (bx & 7) * 8 + ((bx >> 3) >> 4);   // 0..63
  const int qt = (bx >> 3) & 15;
  const int b = g >> 1, hp = g & 1;
  const int h = hp * 4 + wv;
  const size_t hb = (size_t)b * Hn + h;
  const int qt0 = qt * 16;
  const unsigned short* qp = q_ws + (hb*Nn + qt0 + lm) * Dn;   // q pre-scaled 1/8
  const bf16x8 qa0 = *(const bf16x8*)(qp + quad*8);
  const bf16x8 qa1 = *(const bf16x8*)(qp + 32 + quad*8);
  const unsigned short* bt = bias16 + (hb*16 + qt) * 4096 + (size_t)lane*4;
  // packed bases: K'[(hb*8+dg)*256+key]*8 ; V'[(hb*32+kg)*64+d]*8
  const unsigned short* kb = k_ws + ((hb*8 + quad)*256 + lm) * 8;
  const unsigned short* vb = v_ws + ((hb*32 + quad)*64 + lm) * 8;
  f32x4 oa[4] = {};
  float esum[4] = {0.f, 0.f, 0.f, 0.f};
  // pipeline registers: chunk-ck K frags (dg=quad / quad+4, keys lm / lm+16)
  bf16x8 kf0 = *(const bf16x8*)(kb);
  bf16x8 kf1 = *(const bf16x8*)(kb + 8192);        // dg += 4 (d 32..63)
  bf16x8 kf2 = *(const bf16x8*)(kb + 128);         // key += 16
  bf16x8 kf3 = *(const bf16x8*)(kb + 8192 + 128);
  h4f hv0 = *(const h4f*)(bt);
  h4f hv1 = *(const h4f*)(bt + 256);
  #pragma unroll 2
  for (int ck = 0; ck < 8; ++ck) {
    // V loads for THIS chunk issue first: in flight during QK^T + softmax
    const unsigned short* vp = vb + ck*2048;       // kg = ck*4 + quad
    const bf16x8 bv0 = *(const bf16x8*)(vp);
    const bf16x8 bv1 = *(const bf16x8*)(vp + 128); // d += 16
    const bf16x8 bv2 = *(const bf16x8*)(vp + 256);
    const bf16x8 bv3 = *(const bf16x8*)(vp + 384);
    // QK^T from registers prefetched last iteration (bias as C-init)
    f32x4 la0, la1;
    #pragma unroll
    for (int r = 0; r < 4; ++r) { la0[r] = (float)hv0[r]; la1[r] = (float)hv1[r]; }
    __builtin_amdgcn_s_setprio(1);
    la0 = __builtin_amdgcn_mfma_f32_16x16x32_bf16(qa0, kf0, la0, 0, 0, 0);
    la0 = __builtin_amdgcn_mfma_f32_16x16x32_bf16(qa1, kf1, la0, 0, 0, 0);
    la1 = __builtin_amdgcn_mfma_f32_16x16x32_bf16(qa0, kf2, la1, 0, 0, 0);
    la1 = __builtin_amdgcn_mfma_f32_16x16x32_bf16(qa1, kf3, la1, 0, 0, 0);
    __builtin_amdgcn_s_setprio(0);
    // prefetch NEXT chunk K + bias: in flight during exp/pack/PV below
    if (ck < 7) {
      const unsigned short* kn = kb + (ck + 1) * 256;   // key += 32
      kf0 = *(const bf16x8*)(kn);
      kf1 = *(const bf16x8*)(kn + 8192);
      kf2 = *(const bf16x8*)(kn + 128);
      kf3 = *(const bf16x8*)(kn + 8192 + 128);
      hv0 = *(const h4f*)(bt + (ck + 1) * 512);
      hv1 = *(const h4f*)(bt + (ck + 1) * 512 + 256);
    }
    // max-free softmax: P = exp(logit); lane-local denominator accumulation
    #pragma unroll
    for (int r = 0; r < 4; ++r) {
      la0[r] = __expf(la0[r]);
      la1[r] = __expf(la1[r]);
      esum[r] += la0[r] + la1[r];
    }
    // pack P (bf16) C-layout -> per-wave strip (wave-internal, no barrier)
    const int ps = ck & 1;
    #pragma unroll
    for (int r = 0; r < 4; ++r) {
      s_p[wv][ps][quad*4+r][lm]      = f2bf(la0[r]);
      s_p[wv][ps][quad*4+r][16 + lm] = f2bf(la1[r]);
    }
    const bf16x8 ap = *(const bf16x8*)&s_p[wv][ps][lm][quad*8];
    __builtin_amdgcn_s_setprio(1);
    oa[0] = __builtin_amdgcn_mfma_f32_16x16x32_bf16(ap, bv0, oa[0], 0, 0, 0);
    oa[1] = __builtin_amdgcn_mfma_f32_16x16x32_bf16(ap, bv1, oa[1], 0, 0, 0);
    oa[2] = __builtin_amdgcn_mfma_f32_16x16x32_bf16(ap, bv2, oa[2], 0, 0, 0);
    oa[3] = __builtin_amdgcn_mfma_f32_16x16x32_bf16(ap, bv3, oa[3], 0, 0, 0);
    __builtin_amdgcn_s_setprio(0);
  }
  // finalize: one cross-lane sum per row, normalize, store
  #pragma unroll
  for (int r = 0; r < 4; ++r) {
    float s = esum[r];
    #pragma unroll
    for (int msk = 1; msk < 16; msk <<= 1) s += __shfl_xor(s, msk);
    const float inv = 1.0f / s;
    const int n = qt0 + quad*4 + r;
    #pragma unroll
    for (int nt = 0; nt < 4; ++nt)
      o_ws[((size_t)(b*Nn + n))*En + h*64 + nt*16 + lm] = f2bf(oa[nt][r] * inv);
  }
}

// ---------------------------------------------------------------------------
// Fallback kernels (workspace too small). Old layouts, self-consistent.
// ---------------------------------------------------------------------------
__global__ __launch_bounds__(256) void qkv_gemm(
    const unsigned short* __restrict__ xb, const float* __restrict__ wq,
    const float* __restrict__ bq,
    unsigned short* __restrict__ q_ws, unsigned short* __restrict__ k_ws,
    unsigned short* __restrict__ v_ws){
  __shared__ unsigned short s_a[128][40];
  __shared__ unsigned short s_b[128][40];
  const int tid = threadIdx.x;
  const int bx = blockIdx.x;
  const int by = blockIdx.y;
  const int row0 = by * 128, n0 = bx * 128;
  const int lane = tid & 63, wv = tid >> 6;
  const int wr = wv >> 1, wc = wv & 1;
  const int lm = lane & 15, quad = lane >> 4;
  const int sr = tid >> 3, sc4 = (tid & 7) * 4;
  f32x4 acc[4][4] = {};
  for (int kc = 0; kc < 16; ++kc) {
    const int k0 = kc * 32;
    __syncthreads();
    #pragma unroll
    for (int i = 0; i < 2; ++i) {
      int g = tid * 2 + i;
      int r = g >> 2, c8 = (g & 3) * 8;
      *(bf16x8*)&s_a[r][c8] = *(const bf16x8*)(xb + (size_t)(row0 + r)*512 + k0 + c8);
    }
    #pragma unroll
    for (int i = 0; i < 4; ++i) {
      int r = sr + i * 32;
      float4 vb = *(const float4*)(wq + (size_t)(n0 + r) * 512 + k0 + sc4);
      bf16x4 pb;
      pb[0]=(short)f2bf(vb.x); pb[1]=(short)f2bf(vb.y); pb[2]=(short)f2bf(vb.z); pb[3]=(short)f2bf(vb.w);
      *(bf16x4*)&s_b[r][sc4] = pb;
    }
    __syncthreads();
    bf16x8 af[4], bfr[4];
    #pragma unroll
    for (int mt = 0; mt < 4; ++mt) af[mt]  = *(const bf16x8*)&s_a[wr*64 + mt*16 + lm][quad*8];
    #pragma unroll
    for (int nt = 0; nt < 4; ++nt) bfr[nt] = *(const bf16x8*)&s_b[wc*64 + nt*16 + lm][quad*8];
    #pragma unroll
    for (int mt = 0; mt < 4; ++mt)
      #pragma unroll
      for (int nt = 0; nt < 4; ++nt)
        acc[mt][nt] = __builtin_amdgcn_mfma_f32_16x16x32_bf16(af[mt], bfr[nt], acc[mt][nt], 0, 0, 0);
  }
  #pragma unroll
  for (int nt = 0; nt < 4; ++nt) {
    int c = n0 + wc*64 + nt*16 + lm;
    float bias = bq[c];
    int sec = c >> 9, ch = c & 511, h = ch >> 6, d = ch & 63;
    #pragma unroll
    for (int mt = 0; mt < 4; ++mt) {
      #pragma unroll
      for (int r = 0; r < 4; ++r) {
        int grow = row0 + wr*64 + mt*16 + quad*4 + r;
        int b = grow >> 8, n = grow & 255;
        float val = acc[mt][nt][r] + bias;
        if (sec == 0)      q_ws[(((size_t)b*Hn + h)*Nn + n)*Dn + d] = f2bf(val * 0.125f);
        else if (sec == 1) k_ws[(((size_t)b*Hn + h)*Nn + n)*Dn + d] = f2bf(val);
        else               v_ws[(((size_t)b*Hn + h)*Dn + d)*Nn + n] = f2bf(val);
      }
    }
  }
}

__global__ __launch_bounds__(256) void attn_kernel(
    const float* __restrict__ U, const float* __restrict__ w_u, const float* __restrict__ b_u,
    const unsigned short* __restrict__ q_ws, const unsigned short* __restrict__ k_ws,
    const unsigned short* __restrict__ v_ws, unsigned short* __restrict__ o_ws){
  __shared__ unsigned short s_p[4][2][16][40];
  __shared__ float s_wu[64];
  __shared__ float s_bu[8];
  const int tid = threadIdx.x;
  const int wv = tid >> 6, lane = tid & 63;
  const int lm = lane & 15, quad = lane >> 4;
  const int blk = blockIdx.x;
  const int b = blk >> 4, qt0 = (blk & 15) * 16;
  if (tid < 64) s_wu[tid] = w_u[tid];
  if (tid < 8)  s_bu[tid] = b_u[tid];
  __syncthreads();
  const int h0 = wv * 2, h1 = h0 + 1;
  const size_t hb0 = (size_t)b * Hn + h0, hb1 = hb0 + 1;
  float wu0[8], wu1[8];
  #pragma unroll
  for (int i = 0; i < 8; ++i) { wu0[i] = s_wu[h0*8 + i]; wu1[i] = s_wu[h1*8 + i]; }
  const float bu0 = s_bu[h0], bu1 = s_bu[h1];
  const unsigned short* q0p = q_ws + (hb0*Nn + qt0 + lm)*Dn;
  const unsigned short* q1p = q_ws + (hb1*Nn + qt0 + lm)*Dn;
  const bf16x8 qa0 = *(const bf16x8*)(q0p + quad*8);
  const bf16x8 qa1 = *(const bf16x8*)(q0p + 32 + quad*8);
  const bf16x8 qb0 = *(const bf16x8*)(q1p + quad*8);
  const bf16x8 qb1 = *(const bf16x8*)(q1p + 32 + quad*8);
  f32x4 oa[4] = {}, ob[4] = {};
  float m0[4], m1[4], l0[4], l1[4];
  #pragma unroll
  for (int r = 0; r < 4; ++r) { m0[r] = m1[r] = -3.0e38f; l0[r] = l1[r] = 0.f; }
  const float* Ub = U + ((size_t)(b*Nn + qt0)) * Nn * 8;
  #pragma unroll 1
  for (int ck = 0; ck < 8; ++ck) {
    f32x4 la0, la1, lb0, lb1;
    #pragma unroll
    for (int t = 0; t < 2; ++t) {
      const int key0 = ck*32 + t*16;
      f32x4 c0, c1;
      #pragma unroll
      for (int r = 0; r < 4; ++r) {
        const float4* up = (const float4*)(Ub + ((size_t)(quad*4+r)*Nn + key0 + lm)*8);
        float4 ua = up[0], uc = up[1];
        c0[r] = bu0 + ua.x*wu0[0] + ua.y*wu0[1] + ua.z*wu0[2] + ua.w*wu0[3]
                    + uc.x*wu0[4] + uc.y*wu0[5] + uc.z*wu0[6] + uc.w*wu0[7];
        c1[r] = bu1 + ua.x*wu1[0] + ua.y*wu1[1] + ua.z*wu1[2] + ua.w*wu1[3]
                    + uc.x*wu1[4] + uc.y*wu1[5] + uc.z*wu1[6] + uc.w*wu1[7];
      }
      const unsigned short* k0p = k_ws + (hb0*Nn + key0 + lm)*Dn;
      const unsigned short* k1p = k_ws + (hb1*Nn + key0 + lm)*Dn;
      bf16x8 kf;
      kf = *(const bf16x8*)(k0p + quad*8);
      c0 = __builtin_amdgcn_mfma_f32_16x16x32_bf16(qa0, kf, c0, 0, 0, 0);
      kf = *(const bf16x8*)(k0p + 32 + quad*8);
      c0 = __builtin_amdgcn_mfma_f32_16x16x32_bf16(qa1, kf, c0, 0, 0, 0);
      kf = *(const bf16x8*)(k1p + quad*8);
      c1 = __builtin_amdgcn_mfma_f32_16x16x32_bf16(qb0, kf, c1, 0, 0, 0);
      kf = *(const bf16x8*)(k1p + 32 + quad*8);
      c1 = __builtin_amdgcn_mfma_f32_16x16x32_bf16(qb1, kf, c1, 0, 0, 0);
      if (t == 0) { la0 = c0; lb0 = c1; } else { la1 = c0; lb1 = c1; }
    }
    #pragma unroll
    for (int r = 0; r < 4; ++r) {
      {
        float tm = fmaxf(la0[r], la1[r]);
        #pragma unroll
        for (int msk = 1; msk < 16; msk <<= 1) tm = fmaxf(tm, __shfl_xor(tm, msk));
        float mn = fmaxf(m0[r], tm);
        float al = __expf(m0[r] - mn);
        m0[r] = mn;
        float e0 = __expf(la0[r] - mn), e1 = __expf(la1[r] - mn);
        la0[r] = e0; la1[r] = e1;
        float s = e0 + e1;
        #pragma unroll
        for (int msk = 1; msk < 16; msk <<= 1) s += __shfl_xor(s, msk);
        l0[r] = l0[r] * al + s;
        #pragma unroll
        for (int nt = 0; nt < 4; ++nt) oa[nt][r] *= al;
      }
      {
        float tm = fmaxf(lb0[r], lb1[r]);
        #pragma unroll
        for (int msk = 1; msk < 16; msk <<= 1) tm = fmaxf(tm, __shfl_xor(tm, msk));
        float mn = fmaxf(m1[r], tm);
        float al = __expf(m1[r] - mn);
        m1[r] = mn;
        float e0 = __expf(lb0[r] - mn), e1 = __expf(lb1[r] - mn);
        lb0[r] = e0; lb1[r] = e1;
        float s = e0 + e1;
        #pragma unroll
        for (int msk = 1; msk < 16; msk <<= 1) s += __shfl_xor(s, msk);
        l1[r] = l1[r] * al + s;
        #pragma unroll
        for (int nt = 0; nt < 4; ++nt) ob[nt][r] *= al;
      }
    }
    #pragma unroll
    for (int r = 0; r < 4; ++r) {
      s_p[wv][0][quad*4+r][lm]      = f2bf(la0[r]);
      s_p[wv][0][quad*4+r][16 + lm] = f2bf(la1[r]);
      s_p[wv][1][quad*4+r][lm]      = f2bf(lb0[r]);
      s_p[wv][1][quad*4+r][16 + lm] = f2bf(lb1[r]);
    }
    const bf16x8 ap0 = *(const bf16x8*)&s_p[wv][0][lm][quad*8];
    const bf16x8 ap1 = *(const bf16x8*)&s_p[wv][1][lm][quad*8];
    #pragma unroll
    for (int nt = 0; nt < 4; ++nt) {
      bf16x8 bv = *(const bf16x8*)(v_ws + (hb0*Dn + nt*16 + lm)*Nn + ck*32 + quad*8);
      oa[nt] = __builtin_amdgcn_mfma_f32_16x16x32_bf16(ap0, bv, oa[nt], 0, 0, 0);
      bv = *(const bf16x8*)(v_ws + (hb1*Dn + nt*16 + lm)*Nn + ck*32 + quad*8);
      ob[nt] = __builtin_amdgcn_mfma_f32_16x16x32_bf16(ap1, bv, ob[nt], 0, 0, 0);
    }
  }
  #pragma unroll
  for (int r = 0; r < 4; ++r) {
    const float i0 = 1.0f / l0[r], i1 = 1.0f / l1[r];
    const int n = qt0 + quad*4 + r;
    #pragma unroll
    for (int nt = 0; nt < 4; ++nt) {
      o_ws[((size_t)(b*Nn + n))*En + h0*64 + nt*16 + lm] = f2bf(oa[nt][r] * i0);
      o_ws[((size_t)(b*Nn + n))*En + h1*64 + nt*16 + lm] = f2bf(ob[nt][r] * i1);
    }
  }
}

__global__ __launch_bounds__(256) void oproj_gemm(
    const unsigned short* __restrict__ o_ws, const float* __restrict__ wo,
    const float* __restrict__ bo, float* __restrict__ out){
  __shared__ unsigned short s_a[128][40];
  __shared__ unsigned short s_b[128][40];
  const int tid = threadIdx.x;
  const int bx = blockIdx.x;
  const int by = blockIdx.y;
  const int row0 = by * 128, n0 = bx * 128;
  const int lane = tid & 63, wv = tid >> 6;
  const int wr = wv >> 1, wc = wv & 1;
  const int lm = lane & 15, quad = lane >> 4;
  const int sr = tid >> 3, sc4 = (tid & 7) * 4;
  f32x4 acc[4][4] = {};
  for (int kc = 0; kc < 16; ++kc) {
    const int k0 = kc * 32;
    __syncthreads();
    #pragma unroll
    for (int i = 0; i < 2; ++i) {
      int g = tid * 2 + i;
      int r = g >> 2, c8 = (g & 3) * 8;
      *(bf16x8*)&s_a[r][c8] = *(const bf16x8*)(o_ws + (size_t)(row0 + r)*512 + k0 + c8);
    }
    #pragma unroll
    for (int i = 0; i < 4; ++i) {
      int r = sr + i * 32;
      float4 vb = *(const float4*)(wo + (size_t)(n0 + r) * 512 + k0 + sc4);
      bf16x4 pb;
      pb[0]=(short)f2bf(vb.x); pb[1]=(short)f2bf(vb.y); pb[2]=(short)f2bf(vb.z); pb[3]=(short)f2bf(vb.w);
      *(bf16x4*)&s_b[r][sc4] = pb;
    }
    __syncthreads();
    bf16x8 af[4], bfr[4];
    #pragma unroll
    for (int mt = 0; mt < 4; ++mt) af[mt]  = *(const bf16x8*)&s_a[wr*64 + mt*16 + lm][quad*8];
    #pragma unroll
    for (int nt = 0; nt < 4; ++nt) bfr[nt] = *(const bf16x8*)&s_b[wc*64 + nt*16 + lm][quad*8];
    #pragma unroll
    for (int mt = 0; mt < 4; ++mt)
      #pragma unroll
      for (int nt = 0; nt < 4; ++nt)
        acc[mt][nt] = __builtin_amdgcn_mfma_f32_16x16x32_bf16(af[mt], bfr[nt], acc[mt][nt], 0, 0, 0);
  }
  #pragma unroll
  for (int nt = 0; nt < 4; ++nt) {
    int c = n0 + wc*64 + nt*16 + lm;
    float bias = bo[c];
    #pragma unroll
    for (int mt = 0; mt < 4; ++mt)
      #pragma unroll
      for (int r = 0; r < 4; ++r) {
        int grow = row0 + wr*64 + mt*16 + quad*4 + r;
        out[(size_t)grow*512 + c] = acc[mt][nt][r] + bias;
      }
  }
}

extern "C" void kernel_launch(void* const* d_in, const int* in_sizes, int n_in,
                              void* d_out, int out_size, void* d_ws, size_t ws_size,
                              hipStream_t stream) {
  const float* x     = (const float*)d_in[0];
  const float* U     = (const float*)d_in[1];
  const float* w_qkv = (const float*)d_in[2];
  const float* b_qkv = (const float*)d_in[3];
  const float* w_out = (const float*)d_in[4];
  const float* b_out = (const float*)d_in[5];
  const float* w_u   = (const float*)d_in[6];
  const float* b_u   = (const float*)d_in[7];
  float* out = (float*)d_out;

  const size_t per = (size_t)Bn * Hn * Nn * Dn;       // 4,194,304 elements
  unsigned short* q_ws = (unsigned short*)d_ws;
  unsigned short* k_ws = q_ws + per;
  unsigned short* v_ws = k_ws + per;                  // packed V' (fast) / [B,H,D,N] (fallback)
  unsigned short* o_ws = v_ws + per;                  // [B,N,E]; doubles as x_bf16 before attn
  unsigned short* bias16 = o_ws + per;                // fp16 frag-packed bias, 32 MiB
  unsigned short* wqb = bias16 + (size_t)Bn*Hn*Nn*Nn; // bf16 w_qkv, 1.5 MiB
  unsigned short* wob = wqb + (size_t)3*En*En;        // bf16 w_out, 0.5 MiB

  const size_t need = (per*4 + (size_t)Bn*Hn*Nn*Nn + (size_t)3*En*En + (size_t)En*En) * 2;

  if (ws_size >= need) {
    convert_all<<<dim3(2560),  dim3(256), 0, stream>>>(x, o_ws, w_qkv, wqb, w_out, wob);
    qkv_bias_gemm<<<dim3(2816), dim3(256), 0, stream>>>(o_ws, wqb, b_qkv, U, w_u, b_u,
                                                        q_ws, k_ws, v_ws, bias16);
    attn_fast <<<dim3(1024),   dim3(256), 0, stream>>>(bias16, q_ws, k_ws, v_ws, o_ws);
    oproj_gemm4<<<dim3(8, 64), dim3(256), 0, stream>>>(o_ws, wob, b_out, out);
  } else {
    convert_x <<<dim3(2048),  dim3(256), 0, stream>>>(x, o_ws);
    qkv_gemm  <<<dim3(12, 64), dim3(256), 0, stream>>>(o_ws, w_qkv, b_qkv, q_ws, k_ws, v_ws);
    attn_kernel<<<dim3(Bn * 16), dim3(256), 0, stream>>>(U, w_u, b_u, q_ws, k_ws, v_ws, o_ws);
    oproj_gemm<<<dim3(4, 64), dim3(256), 0, stream>>>(o_ws, w_out, b_out, out);
  }
}

// Round 13
// 178.864 us; speedup vs baseline: 1.0883x; 1.0094x over previous
//
#include <hip/hip_runtime.h>
#include <stdint.h>

#define Bn 32
#define Nn 256
#define En 512
#define Hn 8
#define Dn 64

typedef __attribute__((ext_vector_type(8))) short bf16x8;   // MFMA A/B frag (4 VGPRs)
typedef __attribute__((ext_vector_type(4))) short bf16x4;
typedef __attribute__((ext_vector_type(4))) float f32x4;    // MFMA C/D frag
typedef __attribute__((ext_vector_type(4))) _Float16 h4f;   // packed fp16 bias frag

__device__ __forceinline__ unsigned short f2bf(float f){
  union{float f; uint32_t i;} v; v.f = f;
  uint32_t i = v.i;
  return (unsigned short)((i + 0x7fffu + ((i>>16)&1u)) >> 16);  // RNE
}

// async global->LDS, 16B per lane. LDS dest = wave-uniform base + lane*16.
__device__ __forceinline__ void stage16(const unsigned short* g,
                                        unsigned short* lds_wave_base,
                                        unsigned short* lds_lane){
#if __has_builtin(__builtin_amdgcn_global_load_lds)
  __builtin_amdgcn_global_load_lds(
      (const __attribute__((address_space(1))) unsigned int*)g,
      (__attribute__((address_space(3))) unsigned int*)lds_wave_base, 16, 0, 0);
  (void)lds_lane;
#else
  *(bf16x8*)lds_lane = *(const bf16x8*)g;
  (void)lds_wave_base;
#endif
}

// ---------------------------------------------------------------------------
// Kernel 0 (fallback path): x fp32 -> bf16.
// ---------------------------------------------------------------------------
__global__ __launch_bounds__(256) void convert_x(
    const float* __restrict__ x, unsigned short* __restrict__ xb){
  size_t i = ((size_t)blockIdx.x * 256 + threadIdx.x) * 8;
  float4 a = *(const float4*)(x + i);
  float4 b = *(const float4*)(x + i + 4);
  bf16x8 p;
  p[0]=(short)f2bf(a.x); p[1]=(short)f2bf(a.y); p[2]=(short)f2bf(a.z); p[3]=(short)f2bf(a.w);
  p[4]=(short)f2bf(b.x); p[5]=(short)f2bf(b.y); p[6]=(short)f2bf(b.z); p[7]=(short)f2bf(b.w);
  *(bf16x8*)(xb + i) = p;
}

// ---------------------------------------------------------------------------
// Kernel P-v2: conversions ONLY (unchanged, verified).
// ---------------------------------------------------------------------------
__global__ __launch_bounds__(256) void convert_all(
    const float* __restrict__ x, unsigned short* __restrict__ xb,
    const float* __restrict__ wq, unsigned short* __restrict__ wqb,
    const float* __restrict__ wo, unsigned short* __restrict__ wob){
  const int bx = blockIdx.x;
  const int tid = threadIdx.x;
  const float* src; unsigned short* dst; size_t i;
  if (bx < 2048)      { src = x;  dst = xb;  i = ((size_t)bx * 256 + tid) * 8; }
  else if (bx < 2432) { src = wq; dst = wqb; i = ((size_t)(bx-2048) * 256 + tid) * 8; }
  else                { src = wo; dst = wob; i = ((size_t)(bx-2432) * 256 + tid) * 8; }
  float4 a = *(const float4*)(src + i);
  float4 b = *(const float4*)(src + i + 4);
  bf16x8 p;
  p[0]=(short)f2bf(a.x); p[1]=(short)f2bf(a.y); p[2]=(short)f2bf(a.z); p[3]=(short)f2bf(a.w);
  p[4]=(short)f2bf(b.x); p[5]=(short)f2bf(b.y); p[6]=(short)f2bf(b.z); p[7]=(short)f2bf(b.w);
  *(bf16x8*)(dst + i) = p;
}

// ---------------------------------------------------------------------------
// Kernel A-v10: DEPTH-2 pipeline, BK=32, 3 LDS buffers (48 KB -> 3 blocks/CU).
// Stage tiles k+1 AND k+2 before computing tile k: steady-state wait
// vmcnt(8) (= 2 tiles in flight), tail vmcnt(4)/vmcnt(0). Swizzle is
// round-7's verified BK=32 pattern (measured 0 bank conflicts). Epilogue =
// round-12's verified packed K'/V' stores. Bias blocks unchanged.
// ---------------------------------------------------------------------------
__global__ __launch_bounds__(256) void qkv_bias_gemm(
    const unsigned short* __restrict__ xb, const unsigned short* __restrict__ wqb,
    const float* __restrict__ bq,
    const float* __restrict__ U, const float* __restrict__ w_u,
    const float* __restrict__ b_u,
    unsigned short* __restrict__ q_ws, unsigned short* __restrict__ k_ws,
    unsigned short* __restrict__ v_ws, unsigned short* __restrict__ bias16){
  __shared__ unsigned short smem[24576];   // 48 KB: A 3x8KB | B 3x8KB; epi [128][136]=34KB
  const int tid = threadIdx.x;
  const int blk = blockIdx.x;

  if (blk >= 768) {
    // ---- bias blocks (verified body) ----
    float* s_wu = (float*)smem;
    float* s_bu = (float*)(smem + 128);
    if (tid < 64) s_wu[tid] = w_u[tid];
    if (tid < 8)  s_bu[tid] = b_u[tid];
    __syncthreads();
    const int t  = (blk - 768) * 256 + tid;      // 0..524287
    const int m_ = t & 255;
    const int n4 = (t >> 8) & 63;                // n = n4*4 + r
    const int bb = t >> 14;                      // batch
    const float* up = U + ((size_t)(bb*Nn + n4*4)*Nn + m_) * 8;
    float u[4][8];
    #pragma unroll
    for (int r = 0; r < 4; ++r) {
      float4 a = *(const float4*)(up + (size_t)r * (Nn*8));
      float4 c = *(const float4*)(up + (size_t)r * (Nn*8) + 4);
      u[r][0]=a.x; u[r][1]=a.y; u[r][2]=a.z; u[r][3]=a.w;
      u[r][4]=c.x; u[r][5]=c.y; u[r][6]=c.z; u[r][7]=c.w;
    }
    const int    lane_in = ((n4 & 3) * 16 + (m_ & 15)) * 4;
    const size_t tbase   = ((size_t)(n4 >> 2) * 16 + (m_ >> 4)) * 256;
    #pragma unroll
    for (int h = 0; h < 8; ++h) {
      const float bu = s_bu[h];
      float acc[4];
      #pragma unroll
      for (int r = 0; r < 4; ++r) {
        float a = bu;
        #pragma unroll
        for (int id = 0; id < 8; ++id) a += u[r][id] * s_wu[h*8 + id];
        acc[r] = a;
      }
      h4f hv;
      hv[0]=(_Float16)acc[0]; hv[1]=(_Float16)acc[1];
      hv[2]=(_Float16)acc[2]; hv[3]=(_Float16)acc[3];
      *(h4f*)(bias16 + (size_t)(bb*Hn + h) * 65536 + tbase + lane_in) = hv;
    }
    return;
  }

  // ---- qkv blocks: 128x128 tile, BK=32, depth-2 counted-vmcnt pipeline ----
  const int bx = blk % 12;              // col tile 0..11
  const int by = blk / 12;              // row tile 0..63
  const int row0 = by * 128, n0 = bx * 128;
  const int lane = tid & 63, wv = tid >> 6;
  const int wr = wv >> 1, wc = wv & 1;
  const int lm = lane & 15, quad = lane >> 4;
  f32x4 acc[4][4] = {};

  // stage K-tile kc (128x32 A + 128x32 B = 4 loads/thread) into buffer buf
  auto stage_tile = [&](int buf, int kc){
    const int k0 = kc * 32;
    unsigned short* sa = smem + buf * 4096;
    unsigned short* sb = smem + 12288 + buf * 4096;
    #pragma unroll
    for (int i = 0; i < 2; ++i) {
      const int ci = i*256 + tid;                  // 16B chunk index 0..511
      const int r = ci >> 2, c = ci & 3;
      const int sc = (c ^ ((r >> 1) & 3)) * 8;     // pre-swizzled source column
      stage16(xb  + (size_t)(row0 + r)*512 + k0 + sc,
              sa + (size_t)(i*256 + wv*64)*8, sa + (size_t)ci*8);
      stage16(wqb + (size_t)(n0  + r)*512 + k0 + sc,
              sb + (size_t)(i*256 + wv*64)*8, sb + (size_t)ci*8);
    }
  };

  stage_tile(0, 0);
  stage_tile(1, 1);                      // prologue: 8 loads in flight (2 tiles)
  #pragma unroll 1
  for (int kc = 0; kc < 16; ++kc) {
    const int cur = kc % 3;
    if (kc < 14) {
      stage_tile((kc + 2) % 3, kc + 2);  // 12 in flight (tiles kc..kc+2)
      asm volatile("s_waitcnt vmcnt(8)" ::: "memory");   // tile kc resident
    } else if (kc == 14) {
      asm volatile("s_waitcnt vmcnt(4)" ::: "memory");   // tiles 14 done, 15 flying
    } else {
      asm volatile("s_waitcnt vmcnt(0)" ::: "memory");
    }
    __builtin_amdgcn_s_barrier();        // all waves: tile kc resident
    __builtin_amdgcn_sched_barrier(0);
    const unsigned short* sa = smem + cur * 4096;
    const unsigned short* sb = smem + 12288 + cur * 4096;
    bf16x8 af[4], bfr[4];
    #pragma unroll
    for (int mt = 0; mt < 4; ++mt) {
      const int r = wr*64 + mt*16 + lm;
      af[mt] = *(const bf16x8*)(sa + (size_t)r*32 + ((quad ^ ((r >> 1) & 3)) * 8));
    }
    #pragma unroll
    for (int nt = 0; nt < 4; ++nt) {
      const int r = wc*64 + nt*16 + lm;
      bfr[nt] = *(const bf16x8*)(sb + (size_t)r*32 + ((quad ^ ((r >> 1) & 3)) * 8));
    }
    #pragma unroll
    for (int mt = 0; mt < 4; ++mt)
      #pragma unroll
      for (int nt = 0; nt < 4; ++nt)
        acc[mt][nt] = __builtin_amdgcn_mfma_f32_16x16x32_bf16(af[mt], bfr[nt], acc[mt][nt], 0, 0, 0);
    __builtin_amdgcn_sched_barrier(0);
    __builtin_amdgcn_s_barrier();        // WAR guard for buffer reuse (no drain)
  }

  // ---- epilogue (round-12 verified): LDS bounce -> packed K'/V' stores ----
  const int sec = bx >> 2;               // 0=q 1=k 2=v
  float bias[4];
  #pragma unroll
  for (int nt = 0; nt < 4; ++nt) bias[nt] = bq[n0 + wc*64 + nt*16 + lm];
  unsigned short* tile = smem;           // q/k: [row=n][col=ch]*136; v: [col=ch][row=n]*136
  if (sec < 2) {
    const float scale = (sec == 0) ? 0.125f : 1.0f;
    #pragma unroll
    for (int nt = 0; nt < 4; ++nt) {
      const int col = wc*64 + nt*16 + lm;
      #pragma unroll
      for (int mt = 0; mt < 4; ++mt)
        #pragma unroll
        for (int r = 0; r < 4; ++r) {
          const int row = wr*64 + mt*16 + quad*4 + r;
          tile[row*136 + col] = f2bf((acc[mt][nt][r] + bias[nt]) * scale);
        }
    }
  } else {
    #pragma unroll
    for (int nt = 0; nt < 4; ++nt) {
      const int col = wc*64 + nt*16 + lm;
      #pragma unroll
      for (int mt = 0; mt < 4; ++mt)
        #pragma unroll
        for (int r = 0; r < 4; ++r) {
          const int row = wr*64 + mt*16 + quad*4 + r;
          tile[col*136 + row] = f2bf(acc[mt][nt][r] + bias[nt]);   // transposed
        }
    }
  }
  __syncthreads();
  const int b = row0 >> 8, nbase = row0 & 255;
  if (sec == 0) {
    // q: row-major [b,h,n,d] (read once per attn block; keep)
    #pragma unroll
    for (int it = 0; it < 16; ++it) {
      const int rown = it*8 + (tid >> 5);            // 0..127
      const int col  = (tid & 31) * 4;               // 0..124
      bf16x4 vv = *(const bf16x4*)(tile + rown*136 + col);
      const int ch = (n0 + col) & 511, h = ch >> 6, d = ch & 63;
      const int n = nbase + rown;
      *(bf16x4*)(q_ws + (((size_t)b*Hn + h)*Nn + n)*Dn + d) = vv;
    }
  } else if (sec == 1) {
    // k: packed K'[b,h,dg,key,8]; 16B/lane, lane-contiguous over key
    const int h0k = (n0 - 512) >> 6;                 // two heads h0k, h0k+1
    const size_t hbk = (size_t)b*Hn + h0k;
    #pragma unroll
    for (int it = 0; it < 8; ++it) {
      const int idx = it*256 + tid;
      const int n = idx & 127;                       // key within tile
      const int combo = idx >> 7;                    // 0..15
      const int hh = combo >> 3, dg = combo & 7;
      bf16x8 vv = *(const bf16x8*)(tile + n*136 + hh*64 + dg*8);
      *(bf16x8*)(k_ws + (((hbk + hh)*8 + dg)*256 + nbase + n)*8) = vv;
    }
  } else {
    // v: packed V'[b,h,kg,d,8]; 16B/lane, lane-contiguous over d
    const int h0v = (n0 - 1024) >> 6;
    const size_t hbv = (size_t)b*Hn + h0v;
    #pragma unroll
    for (int it = 0; it < 8; ++it) {
      const int idx = it*256 + tid;
      const int d = idx & 63;
      const int kgl = (idx >> 6) & 15;               // local key-group (128 keys)
      const int hh = idx >> 10;
      bf16x8 vv = *(const bf16x8*)(tile + (hh*64 + d)*136 + kgl*8);
      *(bf16x8*)(v_ws + (((hbv + hh)*32 + (nbase >> 3) + kgl)*64 + d)*8) = vv;
    }
  }
}

// ---------------------------------------------------------------------------
// Kernel C-v4: oproj GEMM with counted-vmcnt pipeline (unchanged, verified).
// ---------------------------------------------------------------------------
__global__ __launch_bounds__(256) void oproj_gemm4(
    const unsigned short* __restrict__ o_ws, const unsigned short* __restrict__ wob,
    const float* __restrict__ bo, float* __restrict__ out){
  __shared__ unsigned short smem[24576];   // A dbuf 2x16KB | B dbuf 2x8KB
  const int tid = threadIdx.x;
  const int bx = blockIdx.x;            // col tile 0..7 (64 wide)
  const int by = blockIdx.y;            // row tile 0..63
  const int row0 = by * 128, n0 = bx * 64;
  const int lane = tid & 63, wv = tid >> 6;
  const int wr = wv >> 1, wc = wv & 1;
  const int lm = lane & 15, quad = lane >> 4;
  f32x4 acc[4][2] = {};

  auto stage_tile = [&](int buf, int kc){
    const int k0 = kc * 64;
    unsigned short* sa = smem + buf * 8192;
    unsigned short* sb = smem + 16384 + buf * 4096;
    #pragma unroll
    for (int i = 0; i < 4; ++i) {                  // A: 128x64 = 1024 chunks
      const int ci = i*256 + tid;
      const int r = ci >> 3, c = ci & 7;
      const int sc = (c ^ (r & 7)) * 8;
      stage16(o_ws + (size_t)(row0 + r)*512 + k0 + sc,
              sa + (size_t)(i*256 + wv*64)*8, sa + (size_t)ci*8);
    }
    #pragma unroll
    for (int i = 0; i < 2; ++i) {                  // B: 64x64 = 512 chunks
      const int ci = i*256 + tid;
      const int r = ci >> 3, c = ci & 7;
      const int sc = (c ^ (r & 7)) * 8;
      stage16(wob + (size_t)(n0 + r)*512 + k0 + sc,
              sb + (size_t)(i*256 + wv*64)*8, sb + (size_t)ci*8);
    }
  };

  stage_tile(0, 0);
  #pragma unroll 1
  for (int kc = 0; kc < 8; ++kc) {
    const int cur = kc & 1;
    if (kc < 7) {
      stage_tile(cur ^ 1, kc + 1);
      asm volatile("s_waitcnt vmcnt(6)" ::: "memory");
    } else {
      asm volatile("s_waitcnt vmcnt(0)" ::: "memory");
    }
    __builtin_amdgcn_s_barrier();
    __builtin_amdgcn_sched_barrier(0);
    const unsigned short* sa = smem + cur * 8192;
    const unsigned short* sb = smem + 16384 + cur * 4096;
    #pragma unroll
    for (int ks = 0; ks < 2; ++ks) {
      bf16x8 af[4], bfr[2];
      #pragma unroll
      for (int mt = 0; mt < 4; ++mt) {
        const int r = wr*64 + mt*16 + lm;
        af[mt] = *(const bf16x8*)(sa + (size_t)r*64 + (((ks*4 + quad) ^ (r & 7)) * 8));
      }
      #pragma unroll
      for (int nt = 0; nt < 2; ++nt) {
        const int r = wc*32 + nt*16 + lm;
        bfr[nt] = *(const bf16x8*)(sb + (size_t)r*64 + (((ks*4 + quad) ^ (r & 7)) * 8));
      }
      #pragma unroll
      for (int mt = 0; mt < 4; ++mt)
        #pragma unroll
        for (int nt = 0; nt < 2; ++nt)
          acc[mt][nt] = __builtin_amdgcn_mfma_f32_16x16x32_bf16(af[mt], bfr[nt], acc[mt][nt], 0, 0, 0);
    }
    __builtin_amdgcn_sched_barrier(0);
    __builtin_amdgcn_s_barrier();
  }
  #pragma unroll
  for (int nt = 0; nt < 2; ++nt) {
    int c = n0 + wc*32 + nt*16 + lm;
    float bias = bo[c];
    #pragma unroll
    for (int mt = 0; mt < 4; ++mt)
      #pragma unroll
      for (int r = 0; r < 4; ++r) {
        int grow = row0 + wr*64 + mt*16 + quad*4 + r;
        out[(size_t)grow*512 + c] = acc[mt][nt][r] + bias;
      }
  }
}

// ---------------------------------------------------------------------------
// Kernel B-v5: max-free pipelined flash attention reading PACKED K'/V'
// (unchanged from round 12 — verified, delivered ~-12 µs on attn).
// ---------------------------------------------------------------------------
__global__ __launch_bounds__(256) void attn_fast(
    const unsigned short* __restrict__ bias16,
    const unsigned short* __restrict__ q_ws, const unsigned short* __restrict__ k_ws,
    const unsigned short* __restrict__ v_ws, unsigned short* __restrict__ o_ws){
  __shared__ unsigned short s_p[4][2][16][40];   // per-wave dual P strip
  const int tid = threadIdx.x;
  const int wv = tid >> 6, lane = tid & 63;
  const int lm = lane & 15, quad = lane >> 4;
  const int bx = blockIdx.x;
  const int g  = (bx & 7) * 8 + ((bx >> 3) >> 4);   // 0..63
  const int qt = (bx >> 3) & 15;
  const int b = g >> 1, hp = g & 1;
  const int h = hp * 4 + wv;
  const size_t hb = (size_t)b * Hn + h;
  const int qt0 = qt * 16;
  const unsigned short* qp = q_ws + (hb*Nn + qt0 + lm) * Dn;   // q pre-scaled 1/8
  const bf16x8 qa0 = *(const bf16x8*)(qp + quad*8);
  const bf16x8 qa1 = *(const bf16x8*)(qp + 32 + quad*8);
  const unsigned short* bt = bias16 + (hb*16 + qt) * 4096 + (size_t)lane*4;
  // packed bases: K'[(hb*8+dg)*256+key]*8 ; V'[(hb*32+kg)*64+d]*8
  const unsigned short* kb = k_ws + ((hb*8 + quad)*256 + lm) * 8;
  const unsigned short* vb = v_ws + ((hb*32 + quad)*64 + lm) * 8;
  f32x4 oa[4] = {};
  float esum[4] = {0.f, 0.f, 0.f, 0.f};
  // pipeline registers: chunk-ck K frags (dg=quad / quad+4, keys lm / lm+16)
  bf16x8 kf0 = *(const bf16x8*)(kb);
  bf16x8 kf1 = *(const bf16x8*)(kb + 8192);        // dg += 4 (d 32..63)
  bf16x8 kf2 = *(const bf16x8*)(kb + 128);         // key += 16
  bf16x8 kf3 = *(const bf16x8*)(kb + 8192 + 128);
  h4f hv0 = *(const h4f*)(bt);
  h4f hv1 = *(const h4f*)(bt + 256);
  #pragma unroll 2
  for (int ck = 0; ck < 8; ++ck) {
    // V loads for THIS chunk issue first: in flight during QK^T + softmax
    const unsigned short* vp = vb + ck*2048;       // kg = ck*4 + quad
    const bf16x8 bv0 = *(const bf16x8*)(vp);
    const bf16x8 bv1 = *(const bf16x8*)(vp + 128); // d += 16
    const bf16x8 bv2 = *(const bf16x8*)(vp + 256);
    const bf16x8 bv3 = *(const bf16x8*)(vp + 384);
    // QK^T from registers prefetched last iteration (bias as C-init)
    f32x4 la0, la1;
    #pragma unroll
    for (int r = 0; r < 4; ++r) { la0[r] = (float)hv0[r]; la1[r] = (float)hv1[r]; }
    __builtin_amdgcn_s_setprio(1);
    la0 = __builtin_amdgcn_mfma_f32_16x16x32_bf16(qa0, kf0, la0, 0, 0, 0);
    la0 = __builtin_amdgcn_mfma_f32_16x16x32_bf16(qa1, kf1, la0, 0, 0, 0);
    la1 = __builtin_amdgcn_mfma_f32_16x16x32_bf16(qa0, kf2, la1, 0, 0, 0);
    la1 = __builtin_amdgcn_mfma_f32_16x16x32_bf16(qa1, kf3, la1, 0, 0, 0);
    __builtin_amdgcn_s_setprio(0);
    // prefetch NEXT chunk K + bias: in flight during exp/pack/PV below
    if (ck < 7) {
      const unsigned short* kn = kb + (ck + 1) * 256;   // key += 32
      kf0 = *(const bf16x8*)(kn);
      kf1 = *(const bf16x8*)(kn + 8192);
      kf2 = *(const bf16x8*)(kn + 128);
      kf3 = *(const bf16x8*)(kn + 8192 + 128);
      hv0 = *(const h4f*)(bt + (ck + 1) * 512);
      hv1 = *(const h4f*)(bt + (ck + 1) * 512 + 256);
    }
    // max-free softmax: P = exp(logit); lane-local denominator accumulation
    #pragma unroll
    for (int r = 0; r < 4; ++r) {
      la0[r] = __expf(la0[r]);
      la1[r] = __expf(la1[r]);
      esum[r] += la0[r] + la1[r];
    }
    // pack P (bf16) C-layout -> per-wave strip (wave-internal, no barrier)
    const int ps = ck & 1;
    #pragma unroll
    for (int r = 0; r < 4; ++r) {
      s_p[wv][ps][quad*4+r][lm]      = f2bf(la0[r]);
      s_p[wv][ps][quad*4+r][16 + lm] = f2bf(la1[r]);
    }
    const bf16x8 ap = *(const bf16x8*)&s_p[wv][ps][lm][quad*8];
    __builtin_amdgcn_s_setprio(1);
    oa[0] = __builtin_amdgcn_mfma_f32_16x16x32_bf16(ap, bv0, oa[0], 0, 0, 0);
    oa[1] = __builtin_amdgcn_mfma_f32_16x16x32_bf16(ap, bv1, oa[1], 0, 0, 0);
    oa[2] = __builtin_amdgcn_mfma_f32_16x16x32_bf16(ap, bv2, oa[2], 0, 0, 0);
    oa[3] = __builtin_amdgcn_mfma_f32_16x16x32_bf16(ap, bv3, oa[3], 0, 0, 0);
    __builtin_amdgcn_s_setprio(0);
  }
  // finalize: one cross-lane sum per row, normalize, store
  #pragma unroll
  for (int r = 0; r < 4; ++r) {
    float s = esum[r];
    #pragma unroll
    for (int msk = 1; msk < 16; msk <<= 1) s += __shfl_xor(s, msk);
    const float inv = 1.0f / s;
    const int n = qt0 + quad*4 + r;
    #pragma unroll
    for (int nt = 0; nt < 4; ++nt)
      o_ws[((size_t)(b*Nn + n))*En + h*64 + nt*16 + lm] = f2bf(oa[nt][r] * inv);
  }
}

// ---------------------------------------------------------------------------
// Fallback kernels (workspace too small). Old layouts, self-consistent.
// ---------------------------------------------------------------------------
__global__ __launch_bounds__(256) void qkv_gemm(
    const unsigned short* __restrict__ xb, const float* __restrict__ wq,
    const float* __restrict__ bq,
    unsigned short* __restrict__ q_ws, unsigned short* __restrict__ k_ws,
    unsigned short* __restrict__ v_ws){
  __shared__ unsigned short s_a[128][40];
  __shared__ unsigned short s_b[128][40];
  const int tid = threadIdx.x;
  const int bx = blockIdx.x;
  const int by = blockIdx.y;
  const int row0 = by * 128, n0 = bx * 128;
  const int lane = tid & 63, wv = tid >> 6;
  const int wr = wv >> 1, wc = wv & 1;
  const int lm = lane & 15, quad = lane >> 4;
  const int sr = tid >> 3, sc4 = (tid & 7) * 4;
  f32x4 acc[4][4] = {};
  for (int kc = 0; kc < 16; ++kc) {
    const int k0 = kc * 32;
    __syncthreads();
    #pragma unroll
    for (int i = 0; i < 2; ++i) {
      int g = tid * 2 + i;
      int r = g >> 2, c8 = (g & 3) * 8;
      *(bf16x8*)&s_a[r][c8] = *(const bf16x8*)(xb + (size_t)(row0 + r)*512 + k0 + c8);
    }
    #pragma unroll
    for (int i = 0; i < 4; ++i) {
      int r = sr + i * 32;
      float4 vb = *(const float4*)(wq + (size_t)(n0 + r) * 512 + k0 + sc4);
      bf16x4 pb;
      pb[0]=(short)f2bf(vb.x); pb[1]=(short)f2bf(vb.y); pb[2]=(short)f2bf(vb.z); pb[3]=(short)f2bf(vb.w);
      *(bf16x4*)&s_b[r][sc4] = pb;
    }
    __syncthreads();
    bf16x8 af[4], bfr[4];
    #pragma unroll
    for (int mt = 0; mt < 4; ++mt) af[mt]  = *(const bf16x8*)&s_a[wr*64 + mt*16 + lm][quad*8];
    #pragma unroll
    for (int nt = 0; nt < 4; ++nt) bfr[nt] = *(const bf16x8*)&s_b[wc*64 + nt*16 + lm][quad*8];
    #pragma unroll
    for (int mt = 0; mt < 4; ++mt)
      #pragma unroll
      for (int nt = 0; nt < 4; ++nt)
        acc[mt][nt] = __builtin_amdgcn_mfma_f32_16x16x32_bf16(af[mt], bfr[nt], acc[mt][nt], 0, 0, 0);
  }
  #pragma unroll
  for (int nt = 0; nt < 4; ++nt) {
    int c = n0 + wc*64 + nt*16 + lm;
    float bias = bq[c];
    int sec = c >> 9, ch = c & 511, h = ch >> 6, d = ch & 63;
    #pragma unroll
    for (int mt = 0; mt < 4; ++mt) {
      #pragma unroll
      for (int r = 0; r < 4; ++r) {
        int grow = row0 + wr*64 + mt*16 + quad*4 + r;
        int b = grow >> 8, n = grow & 255;
        float val = acc[mt][nt][r] + bias;
        if (sec == 0)      q_ws[(((size_t)b*Hn + h)*Nn + n)*Dn + d] = f2bf(val * 0.125f);
        else if (sec == 1) k_ws[(((size_t)b*Hn + h)*Nn + n)*Dn + d] = f2bf(val);
        else               v_ws[(((size_t)b*Hn + h)*Dn + d)*Nn + n] = f2bf(val);
      }
    }
  }
}

__global__ __launch_bounds__(256) void attn_kernel(
    const float* __restrict__ U, const float* __restrict__ w_u, const float* __restrict__ b_u,
    const unsigned short* __restrict__ q_ws, const unsigned short* __restrict__ k_ws,
    const unsigned short* __restrict__ v_ws, unsigned short* __restrict__ o_ws){
  __shared__ unsigned short s_p[4][2][16][40];
  __shared__ float s_wu[64];
  __shared__ float s_bu[8];
  const int tid = threadIdx.x;
  const int wv = tid >> 6, lane = tid & 63;
  const int lm = lane & 15, quad = lane >> 4;
  const int blk = blockIdx.x;
  const int b = blk >> 4, qt0 = (blk & 15) * 16;
  if (tid < 64) s_wu[tid] = w_u[tid];
  if (tid < 8)  s_bu[tid] = b_u[tid];
  __syncthreads();
  const int h0 = wv * 2, h1 = h0 + 1;
  const size_t hb0 = (size_t)b * Hn + h0, hb1 = hb0 + 1;
  float wu0[8], wu1[8];
  #pragma unroll
  for (int i = 0; i < 8; ++i) { wu0[i] = s_wu[h0*8 + i]; wu1[i] = s_wu[h1*8 + i]; }
  const float bu0 = s_bu[h0], bu1 = s_bu[h1];
  const unsigned short* q0p = q_ws + (hb0*Nn + qt0 + lm)*Dn;
  const unsigned short* q1p = q_ws + (hb1*Nn + qt0 + lm)*Dn;
  const bf16x8 qa0 = *(const bf16x8*)(q0p + quad*8);
  const bf16x8 qa1 = *(const bf16x8*)(q0p + 32 + quad*8);
  const bf16x8 qb0 = *(const bf16x8*)(q1p + quad*8);
  const bf16x8 qb1 = *(const bf16x8*)(q1p + 32 + quad*8);
  f32x4 oa[4] = {}, ob[4] = {};
  float m0[4], m1[4], l0[4], l1[4];
  #pragma unroll
  for (int r = 0; r < 4; ++r) { m0[r] = m1[r] = -3.0e38f; l0[r] = l1[r] = 0.f; }
  const float* Ub = U + ((size_t)(b*Nn + qt0)) * Nn * 8;
  #pragma unroll 1
  for (int ck = 0; ck < 8; ++ck) {
    f32x4 la0, la1, lb0, lb1;
    #pragma unroll
    for (int t = 0; t < 2; ++t) {
      const int key0 = ck*32 + t*16;
      f32x4 c0, c1;
      #pragma unroll
      for (int r = 0; r < 4; ++r) {
        const float4* up = (const float4*)(Ub + ((size_t)(quad*4+r)*Nn + key0 + lm)*8);
        float4 ua = up[0], uc = up[1];
        c0[r] = bu0 + ua.x*wu0[0] + ua.y*wu0[1] + ua.z*wu0[2] + ua.w*wu0[3]
                    + uc.x*wu0[4] + uc.y*wu0[5] + uc.z*wu0[6] + uc.w*wu0[7];
        c1[r] = bu1 + ua.x*wu1[0] + ua.y*wu1[1] + ua.z*wu1[2] + ua.w*wu1[3]
                    + uc.x*wu1[4] + uc.y*wu1[5] + uc.z*wu1[6] + uc.w*wu1[7];
      }
      const unsigned short* k0p = k_ws + (hb0*Nn + key0 + lm)*Dn;
      const unsigned short* k1p = k_ws + (hb1*Nn + key0 + lm)*Dn;
      bf16x8 kf;
      kf = *(const bf16x8*)(k0p + quad*8);
      c0 = __builtin_amdgcn_mfma_f32_16x16x32_bf16(qa0, kf, c0, 0, 0, 0);
      kf = *(const bf16x8*)(k0p + 32 + quad*8);
      c0 = __builtin_amdgcn_mfma_f32_16x16x32_bf16(qa1, kf, c0, 0, 0, 0);
      kf = *(const bf16x8*)(k1p + quad*8);
      c1 = __builtin_amdgcn_mfma_f32_16x16x32_bf16(qb0, kf, c1, 0, 0, 0);
      kf = *(const bf16x8*)(k1p + 32 + quad*8);
      c1 = __builtin_amdgcn_mfma_f32_16x16x32_bf16(qb1, kf, c1, 0, 0, 0);
      if (t == 0) { la0 = c0; lb0 = c1; } else { la1 = c0; lb1 = c1; }
    }
    #pragma unroll
    for (int r = 0; r < 4; ++r) {
      {
        float tm = fmaxf(la0[r], la1[r]);
        #pragma unroll
        for (int msk = 1; msk < 16; msk <<= 1) tm = fmaxf(tm, __shfl_xor(tm, msk));
        float mn = fmaxf(m0[r], tm);
        float al = __expf(m0[r] - mn);
        m0[r] = mn;
        float e0 = __expf(la0[r] - mn), e1 = __expf(la1[r] - mn);
        la0[r] = e0; la1[r] = e1;
        float s = e0 + e1;
        #pragma unroll
        for (int msk = 1; msk < 16; msk <<= 1) s += __shfl_xor(s, msk);
        l0[r] = l0[r] * al + s;
        #pragma unroll
        for (int nt = 0; nt < 4; ++nt) oa[nt][r] *= al;
      }
      {
        float tm = fmaxf(lb0[r], lb1[r]);
        #pragma unroll
        for (int msk = 1; msk < 16; msk <<= 1) tm = fmaxf(tm, __shfl_xor(tm, msk));
        float mn = fmaxf(m1[r], tm);
        float al = __expf(m1[r] - mn);
        m1[r] = mn;
        float e0 = __expf(lb0[r] - mn), e1 = __expf(lb1[r] - mn);
        lb0[r] = e0; lb1[r] = e1;
        float s = e0 + e1;
        #pragma unroll
        for (int msk = 1; msk < 16; msk <<= 1) s += __shfl_xor(s, msk);
        l1[r] = l1[r] * al + s;
        #pragma unroll
        for (int nt = 0; nt < 4; ++nt) ob[nt][r] *= al;
      }
    }
    #pragma unroll
    for (int r = 0; r < 4; ++r) {
      s_p[wv][0][quad*4+r][lm]      = f2bf(la0[r]);
      s_p[wv][0][quad*4+r][16 + lm] = f2bf(la1[r]);
      s_p[wv][1][quad*4+r][lm]      = f2bf(lb0[r]);
      s_p[wv][1][quad*4+r][16 + lm] = f2bf(lb1[r]);
    }
    const bf16x8 ap0 = *(const bf16x8*)&s_p[wv][0][lm][quad*8];
    const bf16x8 ap1 = *(const bf16x8*)&s_p[wv][1][lm][quad*8];
    #pragma unroll
    for (int nt = 0; nt < 4; ++nt) {
      bf16x8 bv = *(const bf16x8*)(v_ws + (hb0*Dn + nt*16 + lm)*Nn + ck*32 + quad*8);
      oa[nt] = __builtin_amdgcn_mfma_f32_16x16x32_bf16(ap0, bv, oa[nt], 0, 0, 0);
      bv = *(const bf16x8*)(v_ws + (hb1*Dn + nt*16 + lm)*Nn + ck*32 + quad*8);
      ob[nt] = __builtin_amdgcn_mfma_f32_16x16x32_bf16(ap1, bv, ob[nt], 0, 0, 0);
    }
  }
  #pragma unroll
  for (int r = 0; r < 4; ++r) {
    const float i0 = 1.0f / l0[r], i1 = 1.0f / l1[r];
    const int n = qt0 + quad*4 + r;
    #pragma unroll
    for (int nt = 0; nt < 4; ++nt) {
      o_ws[((size_t)(b*Nn + n))*En + h0*64 + nt*16 + lm] = f2bf(oa[nt][r] * i0);
      o_ws[((size_t)(b*Nn + n))*En + h1*64 + nt*16 + lm] = f2bf(ob[nt][r] * i1);
    }
  }
}

__global__ __launch_bounds__(256) void oproj_gemm(
    const unsigned short* __restrict__ o_ws, const float* __restrict__ wo,
    const float* __restrict__ bo, float* __restrict__ out){
  __shared__ unsigned short s_a[128][40];
  __shared__ unsigned short s_b[128][40];
  const int tid = threadIdx.x;
  const int bx = blockIdx.x;
  const int by = blockIdx.y;
  const int row0 = by * 128, n0 = bx * 128;
  const int lane = tid & 63, wv = tid >> 6;
  const int wr = wv >> 1, wc = wv & 1;
  const int lm = lane & 15, quad = lane >> 4;
  const int sr = tid >> 3, sc4 = (tid & 7) * 4;
  f32x4 acc[4][4] = {};
  for (int kc = 0; kc < 16; ++kc) {
    const int k0 = kc * 32;
    __syncthreads();
    #pragma unroll
    for (int i = 0; i < 2; ++i) {
      int g = tid * 2 + i;
      int r = g >> 2, c8 = (g & 3) * 8;
      *(bf16x8*)&s_a[r][c8] = *(const bf16x8*)(o_ws + (size_t)(row0 + r)*512 + k0 + c8);
    }
    #pragma unroll
    for (int i = 0; i < 4; ++i) {
      int r = sr + i * 32;
      float4 vb = *(const float4*)(wo + (size_t)(n0 + r) * 512 + k0 + sc4);
      bf16x4 pb;
      pb[0]=(short)f2bf(vb.x); pb[1]=(short)f2bf(vb.y); pb[2]=(short)f2bf(vb.z); pb[3]=(short)f2bf(vb.w);
      *(bf16x4*)&s_b[r][sc4] = pb;
    }
    __syncthreads();
    bf16x8 af[4], bfr[4];
    #pragma unroll
    for (int mt = 0; mt < 4; ++mt) af[mt]  = *(const bf16x8*)&s_a[wr*64 + mt*16 + lm][quad*8];
    #pragma unroll
    for (int nt = 0; nt < 4; ++nt) bfr[nt] = *(const bf16x8*)&s_b[wc*64 + nt*16 + lm][quad*8];
    #pragma unroll
    for (int mt = 0; mt < 4; ++mt)
      #pragma unroll
      for (int nt = 0; nt < 4; ++nt)
        acc[mt][nt] = __builtin_amdgcn_mfma_f32_16x16x32_bf16(af[mt], bfr[nt], acc[mt][nt], 0, 0, 0);
  }
  #pragma unroll
  for (int nt = 0; nt < 4; ++nt) {
    int c = n0 + wc*64 + nt*16 + lm;
    float bias = bo[c];
    #pragma unroll
    for (int mt = 0; mt < 4; ++mt)
      #pragma unroll
      for (int r = 0; r < 4; ++r) {
        int grow = row0 + wr*64 + mt*16 + quad*4 + r;
        out[(size_t)grow*512 + c] = acc[mt][nt][r] + bias;
      }
  }
}

extern "C" void kernel_launch(void* const* d_in, const int* in_sizes, int n_in,
                              void* d_out, int out_size, void* d_ws, size_t ws_size,
                              hipStream_t stream) {
  const float* x     = (const float*)d_in[0];
  const float* U     = (const float*)d_in[1];
  const float* w_qkv = (const float*)d_in[2];
  const float* b_qkv = (const float*)d_in[3];
  const float* w_out = (const float*)d_in[4];
  const float* b_out = (const float*)d_in[5];
  const float* w_u   = (const float*)d_in[6];
  const float* b_u   = (const float*)d_in[7];
  float* out = (float*)d_out;

  const size_t per = (size_t)Bn * Hn * Nn * Dn;       // 4,194,304 elements
  unsigned short* q_ws = (unsigned short*)d_ws;
  unsigned short* k_ws = q_ws + per;
  unsigned short* v_ws = k_ws + per;                  // packed V' (fast) / [B,H,D,N] (fallback)
  unsigned short* o_ws = v_ws + per;                  // [B,N,E]; doubles as x_bf16 before attn
  unsigned short* bias16 = o_ws + per;                // fp16 frag-packed bias, 32 MiB
  unsigned short* wqb = bias16 + (size_t)Bn*Hn*Nn*Nn; // bf16 w_qkv, 1.5 MiB
  unsigned short* wob = wqb + (size_t)3*En*En;        // bf16 w_out, 0.5 MiB

  const size_t need = (per*4 + (size_t)Bn*Hn*Nn*Nn + (size_t)3*En*En + (size_t)En*En) * 2;

  if (ws_size >= need) {
    convert_all<<<dim3(2560),  dim3(256), 0, stream>>>(x, o_ws, w_qkv, wqb, w_out, wob);
    qkv_bias_gemm<<<dim3(2816), dim3(256), 0, stream>>>(o_ws, wqb, b_qkv, U, w_u, b_u,
                                                        q_ws, k_ws, v_ws, bias16);
    attn_fast <<<dim3(1024),   dim3(256), 0, stream>>>(bias16, q_ws, k_ws, v_ws, o_ws);
    oproj_gemm4<<<dim3(8, 64), dim3(256), 0, stream>>>(o_ws, wob, b_out, out);
  } else {
    convert_x <<<dim3(2048),  dim3(256), 0, stream>>>(x, o_ws);
    qkv_gemm  <<<dim3(12, 64), dim3(256), 0, stream>>>(o_ws, w_qkv, b_qkv, q_ws, k_ws, v_ws);
    attn_kernel<<<dim3(Bn * 16), dim3(256), 0, stream>>>(U, w_u, b_u, q_ws, k_ws, v_ws, o_ws);
    oproj_gemm<<<dim3(4, 64), dim3(256), 0, stream>>>(o_ws, w_out, b_out, out);
  }
}